// Round 1
// baseline (1008.967 us; speedup 1.0000x reference)
//
#include <hip/hip_runtime.h>

// ---------------------------------------------------------------------------
// Fused QKV-projection + attention (B=8, C=2048, N=512), fp32 in/out.
// Precision strategy: fp32 -> fp16 hi/lo split; all GEMM-shaped work runs as
// 3-term (hi*hi + lo*hi + hi*lo) fp16 MFMA with fp32 accumulation (~22-bit
// effective mantissa), required because softmax sees UNSCALED logits ~N(0,512).
// Pipeline: split x/W -> proj q,k (split-stored) & v (transposed) -> flash attn.
// ---------------------------------------------------------------------------

typedef _Float16 half_t;
typedef __attribute__((ext_vector_type(8))) _Float16 half8;
typedef __attribute__((ext_vector_type(4))) _Float16 half4;
typedef __attribute__((ext_vector_type(4))) float    f32x4;

#define MFMA16x32(A_, B_, C_) __builtin_amdgcn_mfma_f32_16x16x32_f16((A_), (B_), (C_), 0, 0, 0)

// ---- split fp32 [rows][cols] -> fp16 [rows][2*cols] = [hi | lo] -------------
__global__ void split_hilo(const float* __restrict__ src, half_t* __restrict__ dst,
                           int rows, int cols) {
  int idx = blockIdx.x * 256 + threadIdx.x;   // 4 elements per thread
  int total = rows * cols / 4;
  if (idx >= total) return;
  f32x4 v = ((const f32x4*)src)[idx];
  int e = idx * 4;
  int r = e / cols, c = e % cols;
  half4 h, l;
#pragma unroll
  for (int j = 0; j < 4; ++j) {
    float f = v[j];
    _Float16 hh = (_Float16)f;       // RNE
    h[j] = hh;
    l[j] = (_Float16)(f - (float)hh);
  }
  *(half4*)&dst[(size_t)r * (2 * cols) + c] = h;
  *(half4*)&dst[(size_t)r * (2 * cols) + c + cols] = l;
}

// ---- projection GEMM: C[M][Nc] = A(ext K=1536) . B(ext K=1536)^T + bias -----
// A: [Ma][1024] = [hi|lo], acol = k & 1023   (hi, lo, hi)
// B: [Nb][1024] = [hi|lo], bcol = k<512 ? k : k-512 (hi, hi, lo)
//   => terms hi*hi, lo*hi, hi*lo  (exact 3-term split product)
// MODE 0: out[t][m]=hi, out[t][m+512]=lo   (q/k, row t = A-row, col m = B-row)
// MODE 1: out[m][t] = f16(val)             (v transposed; m = A-row, t = B-row)
template <int MODE>
__global__ __launch_bounds__(256) void proj_gemm(
    const half_t* __restrict__ A, const half_t* __restrict__ Bm,
    const float* __restrict__ bias, half_t* __restrict__ out) {
  __shared__ half_t At[128 * 64];
  __shared__ half_t Bt[128 * 64];
  const int tid = threadIdx.x;
  const int lane = tid & 63, wv = tid >> 6;
  const int g = lane >> 4, li = lane & 15;
  const int wm = wv >> 1, wn = wv & 1;
  const int M0 = blockIdx.x * 128, N0 = blockIdx.y * 128;

  const f32x4 kZero = {0.f, 0.f, 0.f, 0.f};
  f32x4 acc[4][4];
#pragma unroll
  for (int i = 0; i < 4; ++i)
#pragma unroll
    for (int j = 0; j < 4; ++j) acc[i][j] = kZero;

  for (int kt = 0; kt < 24; ++kt) {
    const int kc = kt * 64;
    const int ab = kc & 1023;
    const int bb = (kc < 512) ? kc : (kc - 512);
    __syncthreads();
    // stage 128x64 A and B tiles; XOR-swizzle 16B blocks to kill read conflicts
#pragma unroll
    for (int s2 = 0; s2 < 4; ++s2) {
      int bid = tid + 256 * s2;          // 0..1023
      int row = bid >> 3, blk = bid & 7; // 8 x 16B blocks per 64-col row
      half8 va = *(const half8*)&A[(size_t)(M0 + row) * 1024 + ab + blk * 8];
      *(half8*)&At[row * 64 + ((blk ^ (row & 7)) * 8)] = va;
      half8 vb = *(const half8*)&Bm[(size_t)(N0 + row) * 1024 + bb + blk * 8];
      *(half8*)&Bt[row * 64 + ((blk ^ (row & 7)) * 8)] = vb;
    }
    __syncthreads();
#pragma unroll
    for (int kk = 0; kk < 2; ++kk) {
      half8 af[4], bf[4];
#pragma unroll
      for (int i = 0; i < 4; ++i) {
        int ar = wm * 64 + i * 16 + li;
        af[i] = *(const half8*)&At[ar * 64 + (((4 * kk + g) ^ (ar & 7)) * 8)];
        int br = wn * 64 + i * 16 + li;
        bf[i] = *(const half8*)&Bt[br * 64 + (((4 * kk + g) ^ (br & 7)) * 8)];
      }
#pragma unroll
      for (int i = 0; i < 4; ++i)
#pragma unroll
        for (int j = 0; j < 4; ++j) acc[i][j] = MFMA16x32(af[i], bf[j], acc[i][j]);
    }
  }

  if (MODE == 0) {
#pragma unroll
    for (int i = 0; i < 4; ++i) {
      int trow = M0 + wm * 64 + i * 16 + 4 * g;  // + r
#pragma unroll
      for (int j = 0; j < 4; ++j) {
        int m = N0 + wn * 64 + j * 16 + li;
        float bs = bias[m];
#pragma unroll
        for (int r = 0; r < 4; ++r) {
          float v = acc[i][j][r] + bs;
          _Float16 hh = (_Float16)v;
          _Float16 ll = (_Float16)(v - (float)hh);
          out[(size_t)(trow + r) * 1024 + m] = hh;
          out[(size_t)(trow + r) * 1024 + m + 512] = ll;
        }
      }
    }
  } else {
#pragma unroll
    for (int i = 0; i < 4; ++i) {
      int m0r = M0 + wm * 64 + i * 16 + 4 * g;
#pragma unroll
      for (int r = 0; r < 4; ++r) {
        int m = m0r + r;
        float bs = bias[m];
#pragma unroll
        for (int j = 0; j < 4; ++j) {
          int t = N0 + wn * 64 + j * 16 + li;
          out[(size_t)m * 16384 + t] = (_Float16)(acc[i][j][r] + bs);
        }
      }
    }
  }
}

// ---- flash attention --------------------------------------------------------
// grid 256: block = (batch b = blk>>5, q-rows c0 = (blk&31)*64), 4 waves x 16 rows.
// qs/ks: [16384][1024] fp16 [hi|lo]; vt: [512][16384] fp16 (v transposed).
// S = 3-term QK^T (K=1536 ext), online softmax, PV in fp16 MFMA.
// Output: d_out[b*1048576 + n*2048 + c]  (reference's transposed layout).
__global__ __launch_bounds__(256, 1) void flash_attn(
    const half_t* __restrict__ qs, const half_t* __restrict__ ks,
    const half_t* __restrict__ vt, float* __restrict__ outp) {
  __shared__ half_t plds[4][16][72];  // per-wave P bounce tile, padded (2-way free)
  const int blk = blockIdx.x;
  const int b = blk >> 5;
  const int c0 = (blk & 31) * 64;
  const int tid = threadIdx.x;
  const int wv = tid >> 6, lane = tid & 63;
  const int g = lane >> 4, li = lane & 15;
  const int qr0 = c0 + wv * 16;

  // Q fragments resident in registers: 16 rows x 1024 cols [hi|lo]
  const half_t* qrow = qs + (size_t)(b * 2048 + qr0 + li) * 1024 + 8 * g;
  half8 qf[32];
#pragma unroll
  for (int kc = 0; kc < 32; ++kc) qf[kc] = *(const half8*)(qrow + kc * 32);

  const f32x4 kZero = {0.f, 0.f, 0.f, 0.f};
  f32x4 o[32];
#pragma unroll
  for (int i = 0; i < 32; ++i) o[i] = kZero;
  float mrow[4] = {-3e38f, -3e38f, -3e38f, -3e38f};
  float lrow[4] = {0.f, 0.f, 0.f, 0.f};

  const half_t* kb = ks + (size_t)b * 2048 * 1024;
  const half_t* vb = vt + (size_t)b * 2048;

  for (int kv0 = 0; kv0 < 2048; kv0 += 64) {
    f32x4 s[4];
#pragma unroll
    for (int u = 0; u < 4; ++u) s[u] = kZero;

    // S^tile = Q . K^T, 3-term ext-K loop (48 chunks of 32)
#pragma unroll
    for (int kc = 0; kc < 48; ++kc) {
      const half8 aq = qf[kc & 31];                       // acol = k & 1023
      const int bc = ((kc < 16) ? kc * 32 : (kc * 32 - 512)) + 8 * g;  // bcol
#pragma unroll
      for (int u = 0; u < 4; ++u) {
        half8 kf = *(const half8*)&kb[(size_t)(kv0 + u * 16 + li) * 1024 + bc];
        s[u] = MFMA16x32(aq, kf, s[u]);
      }
    }

    // online softmax (rows r=0..3 of this lane-group; reduce across 16 lanes)
    float alpha[4];
#pragma unroll
    for (int r = 0; r < 4; ++r) {
      float tm = fmaxf(fmaxf(s[0][r], s[1][r]), fmaxf(s[2][r], s[3][r]));
      tm = fmaxf(tm, __shfl_xor(tm, 1));
      tm = fmaxf(tm, __shfl_xor(tm, 2));
      tm = fmaxf(tm, __shfl_xor(tm, 4));
      tm = fmaxf(tm, __shfl_xor(tm, 8));
      float mn = fmaxf(mrow[r], tm);
      float a = __expf(mrow[r] - mn);
      float p0 = __expf(s[0][r] - mn);
      float p1 = __expf(s[1][r] - mn);
      float p2 = __expf(s[2][r] - mn);
      float p3 = __expf(s[3][r] - mn);
      float rs = p0 + p1 + p2 + p3;
      rs += __shfl_xor(rs, 1);
      rs += __shfl_xor(rs, 2);
      rs += __shfl_xor(rs, 4);
      rs += __shfl_xor(rs, 8);
      lrow[r] = lrow[r] * a + rs;
      mrow[r] = mn;
      alpha[r] = a;
      int prow = 4 * g + r;
      plds[wv][prow][li] = (half_t)p0;
      plds[wv][prow][li + 16] = (half_t)p1;
      plds[wv][prow][li + 32] = (half_t)p2;
      plds[wv][prow][li + 48] = (half_t)p3;
    }
    f32x4 av = {alpha[0], alpha[1], alpha[2], alpha[3]};
#pragma unroll
    for (int i = 0; i < 32; ++i) o[i] *= av;

    __syncthreads();  // P write -> P read (cross-lane within wave)

    half8 pa0 = *(const half8*)&plds[wv][li][8 * g];
    half8 pa1 = *(const half8*)&plds[wv][li][32 + 8 * g];
#pragma unroll
    for (int ns = 0; ns < 32; ++ns) {
      const half_t* vr = vb + (size_t)(ns * 16 + li) * 16384 + kv0 + 8 * g;
      half8 v0 = *(const half8*)(vr);
      half8 v1 = *(const half8*)(vr + 32);
      o[ns] = MFMA16x32(pa0, v0, o[ns]);
      o[ns] = MFMA16x32(pa1, v1, o[ns]);
    }
    __syncthreads();  // keep next tile's P writes behind this tile's reads
  }

  float inv[4];
#pragma unroll
  for (int r = 0; r < 4; ++r) inv[r] = 1.0f / (lrow[r] * 22.62741699796952f);
  float* ob = outp + (size_t)b * 1048576 + qr0 + 4 * g;
#pragma unroll
  for (int ns = 0; ns < 32; ++ns) {
#pragma unroll
    for (int r = 0; r < 4; ++r) {
      ob[(size_t)(ns * 16 + li) * 2048 + r] = o[ns][r] * inv[r];
    }
  }
}

// ---------------------------------------------------------------------------
extern "C" void kernel_launch(void* const* d_in, const int* in_sizes, int n_in,
                              void* d_out, int out_size, void* d_ws, size_t ws_size,
                              hipStream_t stream) {
  const float* x  = (const float*)d_in[0];
  const float* Wq = (const float*)d_in[1];
  const float* bq = (const float*)d_in[2];
  const float* Wk = (const float*)d_in[3];
  const float* bk = (const float*)d_in[4];
  const float* Wv = (const float*)d_in[5];
  const float* bv = (const float*)d_in[6];

  // workspace layout (fp16 elements): needs ~120.6 MB
  half_t* xs  = (half_t*)d_ws;                  // [16384][1024]
  half_t* qsb = xs  + (size_t)16384 * 1024;     // [16384][1024]
  half_t* ksb = qsb + (size_t)16384 * 1024;     // [16384][1024]
  half_t* vtb = ksb + (size_t)16384 * 1024;     // [512][16384]
  half_t* wqs = vtb + (size_t)512 * 16384;      // [512][1024]
  half_t* wks = wqs + (size_t)512 * 1024;
  half_t* wvs = wks + (size_t)512 * 1024;

  split_hilo<<<dim3(16384 * 512 / 4 / 256), 256, 0, stream>>>(x, xs, 16384, 512);
  split_hilo<<<dim3(512 * 512 / 4 / 256), 256, 0, stream>>>(Wq, wqs, 512, 512);
  split_hilo<<<dim3(512 * 512 / 4 / 256), 256, 0, stream>>>(Wk, wks, 512, 512);
  split_hilo<<<dim3(512 * 512 / 4 / 256), 256, 0, stream>>>(Wv, wvs, 512, 512);

  proj_gemm<0><<<dim3(128, 4), 256, 0, stream>>>(xs, wqs, bq, qsb);
  proj_gemm<0><<<dim3(128, 4), 256, 0, stream>>>(xs, wks, bk, ksb);
  proj_gemm<1><<<dim3(4, 128), 256, 0, stream>>>(wvs, xs, bv, vtb);

  flash_attn<<<dim3(256), 256, 0, stream>>>(qsb, ksb, vtb, (float*)d_out);
}

// Round 2
// 732.359 us; speedup vs baseline: 1.3777x; 1.3777x over previous
//
#include <hip/hip_runtime.h>

// ---------------------------------------------------------------------------
// Fused QKV-projection + attention (B=8, C=2048, N=512), fp32 in/out.
// Precision: fp32 -> fp16 hi/lo split; GEMM-shaped work = 3-term
// (hi*hi + lo*hi + hi*lo) fp16 MFMA, fp32 accum (~22-bit effective mantissa),
// needed because softmax sees UNSCALED logits ~N(0,512).
// Round 2: flash_attn rebuilt — K-tile staged in LDS via global_load_lds with
// pre-swizzled source (shared across 4 waves, double-buffered KVBLK=32),
// hi-fragment reuse (2 MFMAs per k_hi read), 4 accumulator chains,
// defer-max softmax (THR=8).
// ---------------------------------------------------------------------------

typedef _Float16 half_t;
typedef __attribute__((ext_vector_type(8))) _Float16 half8;
typedef __attribute__((ext_vector_type(4))) _Float16 half4;
typedef __attribute__((ext_vector_type(4))) float    f32x4;

#define MFMA16x32(A_, B_, C_) __builtin_amdgcn_mfma_f32_16x16x32_f16((A_), (B_), (C_), 0, 0, 0)

__device__ __forceinline__ void gload_lds16(const void* g, void* l) {
  __builtin_amdgcn_global_load_lds(
      (const __attribute__((address_space(1))) void*)g,
      (__attribute__((address_space(3))) void*)l, 16, 0, 0);
}

// ---- split fp32 [rows][cols] -> fp16 [rows][2*cols] = [hi | lo] -------------
__global__ void split_hilo(const float* __restrict__ src, half_t* __restrict__ dst,
                           int rows, int cols) {
  int idx = blockIdx.x * 256 + threadIdx.x;   // 4 elements per thread
  int total = rows * cols / 4;
  if (idx >= total) return;
  f32x4 v = ((const f32x4*)src)[idx];
  int e = idx * 4;
  int r = e / cols, c = e % cols;
  half4 h, l;
#pragma unroll
  for (int j = 0; j < 4; ++j) {
    float f = v[j];
    _Float16 hh = (_Float16)f;       // RNE
    h[j] = hh;
    l[j] = (_Float16)(f - (float)hh);
  }
  *(half4*)&dst[(size_t)r * (2 * cols) + c] = h;
  *(half4*)&dst[(size_t)r * (2 * cols) + c + cols] = l;
}

// ---- projection GEMM: C[M][Nc] = A(ext K=1536) . B(ext K=1536)^T + bias -----
// A: [Ma][1024] = [hi|lo], acol = k & 1023   (hi, lo, hi)
// B: [Nb][1024] = [hi|lo], bcol = k<512 ? k : k-512 (hi, hi, lo)
// MODE 0: out[t][m]=hi, out[t][m+512]=lo   (q/k)
// MODE 1: out[m][t] = f16(val)             (v transposed)
template <int MODE>
__global__ __launch_bounds__(256) void proj_gemm(
    const half_t* __restrict__ A, const half_t* __restrict__ Bm,
    const float* __restrict__ bias, half_t* __restrict__ out) {
  __shared__ half_t At[128 * 64];
  __shared__ half_t Bt[128 * 64];
  const int tid = threadIdx.x;
  const int lane = tid & 63, wv = tid >> 6;
  const int g = lane >> 4, li = lane & 15;
  const int wm = wv >> 1, wn = wv & 1;
  const int M0 = blockIdx.x * 128, N0 = blockIdx.y * 128;

  const f32x4 kZero = {0.f, 0.f, 0.f, 0.f};
  f32x4 acc[4][4];
#pragma unroll
  for (int i = 0; i < 4; ++i)
#pragma unroll
    for (int j = 0; j < 4; ++j) acc[i][j] = kZero;

  for (int kt = 0; kt < 24; ++kt) {
    const int kc = kt * 64;
    const int ab = kc & 1023;
    const int bb = (kc < 512) ? kc : (kc - 512);
    __syncthreads();
#pragma unroll
    for (int s2 = 0; s2 < 4; ++s2) {
      int bid = tid + 256 * s2;
      int row = bid >> 3, blk = bid & 7;
      half8 va = *(const half8*)&A[(size_t)(M0 + row) * 1024 + ab + blk * 8];
      *(half8*)&At[row * 64 + ((blk ^ (row & 7)) * 8)] = va;
      half8 vb = *(const half8*)&Bm[(size_t)(N0 + row) * 1024 + bb + blk * 8];
      *(half8*)&Bt[row * 64 + ((blk ^ (row & 7)) * 8)] = vb;
    }
    __syncthreads();
#pragma unroll
    for (int kk = 0; kk < 2; ++kk) {
      half8 af[4], bf[4];
#pragma unroll
      for (int i = 0; i < 4; ++i) {
        int ar = wm * 64 + i * 16 + li;
        af[i] = *(const half8*)&At[ar * 64 + (((4 * kk + g) ^ (ar & 7)) * 8)];
        int br = wn * 64 + i * 16 + li;
        bf[i] = *(const half8*)&Bt[br * 64 + (((4 * kk + g) ^ (br & 7)) * 8)];
      }
#pragma unroll
      for (int i = 0; i < 4; ++i)
#pragma unroll
        for (int j = 0; j < 4; ++j) acc[i][j] = MFMA16x32(af[i], bf[j], acc[i][j]);
    }
  }

  if (MODE == 0) {
#pragma unroll
    for (int i = 0; i < 4; ++i) {
      int trow = M0 + wm * 64 + i * 16 + 4 * g;
#pragma unroll
      for (int j = 0; j < 4; ++j) {
        int m = N0 + wn * 64 + j * 16 + li;
        float bs = bias[m];
#pragma unroll
        for (int r = 0; r < 4; ++r) {
          float v = acc[i][j][r] + bs;
          _Float16 hh = (_Float16)v;
          _Float16 ll = (_Float16)(v - (float)hh);
          out[(size_t)(trow + r) * 1024 + m] = hh;
          out[(size_t)(trow + r) * 1024 + m + 512] = ll;
        }
      }
    }
  } else {
#pragma unroll
    for (int i = 0; i < 4; ++i) {
      int m0r = M0 + wm * 64 + i * 16 + 4 * g;
#pragma unroll
      for (int r = 0; r < 4; ++r) {
        int m = m0r + r;
        float bs = bias[m];
#pragma unroll
        for (int j = 0; j < 4; ++j) {
          int t = N0 + wn * 64 + j * 16 + li;
          out[(size_t)m * 16384 + t] = (_Float16)(acc[i][j][r] + bs);
        }
      }
    }
  }
}

// ---- flash attention v2 -----------------------------------------------------
// grid 256: block = (batch b = blk>>5, q-rows c0 = (blk&31)*64), 4 waves x 16 rows.
// K-tile (KVBLK=32, hi|lo = 64 KB) double-buffered in LDS via global_load_lds;
// source pre-swizzled (blk ^ (row&7)) == read-side swizzle (conflict-free b128).
// QK: per k_hi fragment read -> 2 MFMAs (q_hi, q_lo); k_lo -> 1 MFMA.
// V read direct from global (L2-resident), P bounced through per-wave LDS tile.
__global__ __launch_bounds__(256, 1) void flash_attn(
    const half_t* __restrict__ qs, const half_t* __restrict__ ks,
    const half_t* __restrict__ vt, float* __restrict__ outp) {
  __shared__ half_t kt[2][32 * 1024];   // 2 x 64 KB (32 rows x 1024 halves hi|lo)
  __shared__ half_t plds[4][16][40];    // per-wave P tile (16 q x 32 kv), pad->40

  const int blk = blockIdx.x;
  const int b = blk >> 5;
  const int c0 = (blk & 31) * 64;
  const int tid = threadIdx.x;
  const int wv = tid >> 6, lane = tid & 63;
  const int g = lane >> 4, li = lane & 15;
  const int qr0 = c0 + wv * 16;

  const half_t* kb = ks + (size_t)b * 2048 * 1024;
  const half_t* vb = vt + (size_t)b * 2048;
  const char* kbytes = (const char*)kb;

  // Q fragments resident in registers: 16 rows x 1024 cols [hi|lo]
  const half_t* qrow = qs + (size_t)(b * 2048 + qr0 + li) * 1024 + 8 * g;
  half8 qf[32];
#pragma unroll
  for (int kc = 0; kc < 32; ++kc) qf[kc] = *(const half8*)(qrow + kc * 32);

  const f32x4 kZero = {0.f, 0.f, 0.f, 0.f};
  f32x4 o[32];
#pragma unroll
  for (int i = 0; i < 32; ++i) o[i] = kZero;
  float mrow[4] = {-3e38f, -3e38f, -3e38f, -3e38f};
  float lrow[4] = {0.f, 0.f, 0.f, 0.f};

  // stage KV-tile (32 rows x 2048 B) into kt[buf]; 64 x 1KB segments, 16/wave.
  // LDS linear: seg*1024 + lane*16  ->  row r = seg>>1, blk' = (seg&1)*64+lane.
  // source blk = blk' ^ (r&7)  (involution; read side applies the same XOR).
  auto STAGE = [&](int kv0s, int bufs) {
#pragma unroll
    for (int i2 = 0; i2 < 16; ++i2) {
      int seg = i2 * 4 + wv;
      int r = seg >> 1;
      int bp = (seg & 1) * 64 + lane;
      int bsrc = bp ^ (r & 7);
      gload_lds16(kbytes + (size_t)(kv0s + r) * 2048 + bsrc * 16,
                  (void*)&kt[bufs][seg * 512]);
    }
  };

  STAGE(0, 0);
  __syncthreads();
  int cur = 0;

  for (int t = 0; t < 64; ++t) {
    const int kv0 = t * 32;
    if (t + 1 < 64) STAGE(kv0 + 32, cur ^ 1);

    // ---- QK: S[16 q][32 kv], ext-K 1536, from LDS K-tile ----
    const half_t* k0 = &kt[cur][(size_t)li * 1024];          // u=0 row
    const half_t* k1 = &kt[cur][(size_t)(16 + li) * 1024];   // u=1 row
    const int x0 = li & 7;           // XOR swizzle for rows li and 16+li (same low3)
    f32x4 s00 = kZero, s01 = kZero, s10 = kZero, s11 = kZero;
#pragma unroll
    for (int c = 0; c < 16; ++c) {
      int bh = ((4 * c + g) ^ x0) * 8;
      half8 kh0 = *(const half8*)&k0[bh];
      half8 kh1 = *(const half8*)&k1[bh];
      s00 = MFMA16x32(qf[c], kh0, s00);
      s01 = MFMA16x32(qf[c + 16], kh0, s01);
      s10 = MFMA16x32(qf[c], kh1, s10);
      s11 = MFMA16x32(qf[c + 16], kh1, s11);
    }
#pragma unroll
    for (int c = 0; c < 16; ++c) {
      int bl = ((64 + 4 * c + g) ^ x0) * 8;
      half8 kl0 = *(const half8*)&k0[bl];
      half8 kl1 = *(const half8*)&k1[bl];
      s00 = MFMA16x32(qf[c], kl0, s00);
      s10 = MFMA16x32(qf[c], kl1, s10);
    }
    f32x4 sv0 = s00 + s01;
    f32x4 sv1 = s10 + s11;

    // ---- online softmax with defer-max (THR=8) ----
    float tm4[4];
#pragma unroll
    for (int r = 0; r < 4; ++r) {
      float tm = fmaxf(sv0[r], sv1[r]);
      tm = fmaxf(tm, __shfl_xor(tm, 1));
      tm = fmaxf(tm, __shfl_xor(tm, 2));
      tm = fmaxf(tm, __shfl_xor(tm, 4));
      tm = fmaxf(tm, __shfl_xor(tm, 8));
      tm4[r] = tm;
    }
    int grow = (tm4[0] > mrow[0] + 8.f) | (tm4[1] > mrow[1] + 8.f) |
               (tm4[2] > mrow[2] + 8.f) | (tm4[3] > mrow[3] + 8.f);
    if (__any(grow)) {
      float alpha[4];
#pragma unroll
      for (int r = 0; r < 4; ++r) {
        float mn = fmaxf(mrow[r], tm4[r]);
        alpha[r] = __expf(mrow[r] - mn);
        mrow[r] = mn;
        lrow[r] *= alpha[r];
      }
      f32x4 av = {alpha[0], alpha[1], alpha[2], alpha[3]};
#pragma unroll
      for (int i = 0; i < 32; ++i) o[i] *= av;
    }
#pragma unroll
    for (int r = 0; r < 4; ++r) {
      float p0 = __expf(sv0[r] - mrow[r]);
      float p1 = __expf(sv1[r] - mrow[r]);
      float rs = p0 + p1;
      rs += __shfl_xor(rs, 1);
      rs += __shfl_xor(rs, 2);
      rs += __shfl_xor(rs, 4);
      rs += __shfl_xor(rs, 8);
      lrow[r] += rs;
      plds[wv][4 * g + r][li] = (half_t)p0;
      plds[wv][4 * g + r][li + 16] = (half_t)p1;
    }

    asm volatile("s_waitcnt lgkmcnt(0)" ::: "memory");  // P visible wave-wide

    // ---- PV: O[16 q][512 n] += P[16][32] . V^T[32][512] (V direct, L2) ----
    half8 pa = *(const half8*)&plds[wv][li][8 * g];
#pragma unroll
    for (int ns = 0; ns < 32; ++ns) {
      half8 v0 = *(const half8*)(vb + (size_t)(ns * 16 + li) * 16384 + kv0 + 8 * g);
      o[ns] = MFMA16x32(pa, v0, o[ns]);
    }

    __syncthreads();  // drain stage loads (vmcnt0) + protect kt[cur] / plds reuse
    cur ^= 1;
  }

  float inv[4];
#pragma unroll
  for (int r = 0; r < 4; ++r) inv[r] = 1.0f / (lrow[r] * 22.62741699796952f);
  float* ob = outp + (size_t)b * 1048576 + qr0 + 4 * g;
#pragma unroll
  for (int ns = 0; ns < 32; ++ns) {
#pragma unroll
    for (int r = 0; r < 4; ++r) {
      ob[(size_t)(ns * 16 + li) * 2048 + r] = o[ns][r] * inv[r];
    }
  }
}

// ---------------------------------------------------------------------------
extern "C" void kernel_launch(void* const* d_in, const int* in_sizes, int n_in,
                              void* d_out, int out_size, void* d_ws, size_t ws_size,
                              hipStream_t stream) {
  const float* x  = (const float*)d_in[0];
  const float* Wq = (const float*)d_in[1];
  const float* bq = (const float*)d_in[2];
  const float* Wk = (const float*)d_in[3];
  const float* bk = (const float*)d_in[4];
  const float* Wv = (const float*)d_in[5];
  const float* bv = (const float*)d_in[6];

  half_t* xs  = (half_t*)d_ws;                  // [16384][1024]
  half_t* qsb = xs  + (size_t)16384 * 1024;     // [16384][1024]
  half_t* ksb = qsb + (size_t)16384 * 1024;     // [16384][1024]
  half_t* vtb = ksb + (size_t)16384 * 1024;     // [512][16384]
  half_t* wqs = vtb + (size_t)512 * 16384;      // [512][1024]
  half_t* wks = wqs + (size_t)512 * 1024;
  half_t* wvs = wks + (size_t)512 * 1024;

  split_hilo<<<dim3(16384 * 512 / 4 / 256), 256, 0, stream>>>(x, xs, 16384, 512);
  split_hilo<<<dim3(512 * 512 / 4 / 256), 256, 0, stream>>>(Wq, wqs, 512, 512);
  split_hilo<<<dim3(512 * 512 / 4 / 256), 256, 0, stream>>>(Wk, wks, 512, 512);
  split_hilo<<<dim3(512 * 512 / 4 / 256), 256, 0, stream>>>(Wv, wvs, 512, 512);

  proj_gemm<0><<<dim3(128, 4), 256, 0, stream>>>(xs, wqs, bq, qsb);
  proj_gemm<0><<<dim3(128, 4), 256, 0, stream>>>(xs, wks, bk, ksb);
  proj_gemm<1><<<dim3(4, 128), 256, 0, stream>>>(wvs, xs, bv, vtb);

  flash_attn<<<dim3(256), 256, 0, stream>>>(qsb, ksb, vtb, (float*)d_out);
}

// Round 3
// 635.739 us; speedup vs baseline: 1.5871x; 1.1520x over previous
//
#include <hip/hip_runtime.h>

// ---------------------------------------------------------------------------
// Fused QKV-projection + attention (B=8, C=2048, N=512), fp32 in/out.
// Precision: fp32 -> fp16 hi/lo split. Projections: full 3-term fp16 MFMA.
// Attention logits: 2.5-term (qh*kh + ql*kh; qh*kl dropped, ~6.6e-3 logit std,
// damped by peaked softmax). Round 3: occupancy-first flash rebuild —
// 512 blocks x 4 waves (kv/n-split wave pairs), 2 blocks/CU + 2 waves/SIMD,
// K-hi-only double-buffered LDS, light s_barriers (no vmcnt drain mid-tile),
// l-sum harvested from the pa fragment, XCD-chunked batch locality.
// ---------------------------------------------------------------------------

typedef _Float16 half_t;
typedef __attribute__((ext_vector_type(8))) _Float16 half8;
typedef __attribute__((ext_vector_type(4))) _Float16 half4;
typedef __attribute__((ext_vector_type(4))) float    f32x4;

#define MFMA16x32(A_, B_, C_) __builtin_amdgcn_mfma_f32_16x16x32_f16((A_), (B_), (C_), 0, 0, 0)

__device__ __forceinline__ void gload_lds16(const void* g, void* l) {
  __builtin_amdgcn_global_load_lds(
      (const __attribute__((address_space(1))) void*)g,
      (__attribute__((address_space(3))) void*)l, 16, 0, 0);
}

// ---- split fp32 [rows][cols] -> fp16 [rows][2*cols] = [hi | lo] -------------
__global__ void split_hilo(const float* __restrict__ src, half_t* __restrict__ dst,
                           int rows, int cols) {
  int idx = blockIdx.x * 256 + threadIdx.x;
  int total = rows * cols / 4;
  if (idx >= total) return;
  f32x4 v = ((const f32x4*)src)[idx];
  int e = idx * 4;
  int r = e / cols, c = e % cols;
  half4 h, l;
#pragma unroll
  for (int j = 0; j < 4; ++j) {
    float f = v[j];
    _Float16 hh = (_Float16)f;
    h[j] = hh;
    l[j] = (_Float16)(f - (float)hh);
  }
  *(half4*)&dst[(size_t)r * (2 * cols) + c] = h;
  *(half4*)&dst[(size_t)r * (2 * cols) + c + cols] = l;
}

// ---- projection GEMM (unchanged from R2) ------------------------------------
template <int MODE>
__global__ __launch_bounds__(256) void proj_gemm(
    const half_t* __restrict__ A, const half_t* __restrict__ Bm,
    const float* __restrict__ bias, half_t* __restrict__ out) {
  __shared__ half_t At[128 * 64];
  __shared__ half_t Bt[128 * 64];
  const int tid = threadIdx.x;
  const int lane = tid & 63, wv = tid >> 6;
  const int g = lane >> 4, li = lane & 15;
  const int wm = wv >> 1, wn = wv & 1;
  const int M0 = blockIdx.x * 128, N0 = blockIdx.y * 128;

  const f32x4 kZero = {0.f, 0.f, 0.f, 0.f};
  f32x4 acc[4][4];
#pragma unroll
  for (int i = 0; i < 4; ++i)
#pragma unroll
    for (int j = 0; j < 4; ++j) acc[i][j] = kZero;

  for (int kt = 0; kt < 24; ++kt) {
    const int kc = kt * 64;
    const int ab = kc & 1023;
    const int bb = (kc < 512) ? kc : (kc - 512);
    __syncthreads();
#pragma unroll
    for (int s2 = 0; s2 < 4; ++s2) {
      int bid = tid + 256 * s2;
      int row = bid >> 3, blk = bid & 7;
      half8 va = *(const half8*)&A[(size_t)(M0 + row) * 1024 + ab + blk * 8];
      *(half8*)&At[row * 64 + ((blk ^ (row & 7)) * 8)] = va;
      half8 vb = *(const half8*)&Bm[(size_t)(N0 + row) * 1024 + bb + blk * 8];
      *(half8*)&Bt[row * 64 + ((blk ^ (row & 7)) * 8)] = vb;
    }
    __syncthreads();
#pragma unroll
    for (int kk = 0; kk < 2; ++kk) {
      half8 af[4], bf[4];
#pragma unroll
      for (int i = 0; i < 4; ++i) {
        int ar = wm * 64 + i * 16 + li;
        af[i] = *(const half8*)&At[ar * 64 + (((4 * kk + g) ^ (ar & 7)) * 8)];
        int br = wn * 64 + i * 16 + li;
        bf[i] = *(const half8*)&Bt[br * 64 + (((4 * kk + g) ^ (br & 7)) * 8)];
      }
#pragma unroll
      for (int i = 0; i < 4; ++i)
#pragma unroll
        for (int j = 0; j < 4; ++j) acc[i][j] = MFMA16x32(af[i], bf[j], acc[i][j]);
    }
  }

  if (MODE == 0) {
#pragma unroll
    for (int i = 0; i < 4; ++i) {
      int trow = M0 + wm * 64 + i * 16 + 4 * g;
#pragma unroll
      for (int j = 0; j < 4; ++j) {
        int m = N0 + wn * 64 + j * 16 + li;
        float bs = bias[m];
#pragma unroll
        for (int r = 0; r < 4; ++r) {
          float v = acc[i][j][r] + bs;
          _Float16 hh = (_Float16)v;
          _Float16 ll = (_Float16)(v - (float)hh);
          out[(size_t)(trow + r) * 1024 + m] = hh;
          out[(size_t)(trow + r) * 1024 + m + 512] = ll;
        }
      }
    }
  } else {
#pragma unroll
    for (int i = 0; i < 4; ++i) {
      int m0r = M0 + wm * 64 + i * 16 + 4 * g;
#pragma unroll
      for (int r = 0; r < 4; ++r) {
        int m = m0r + r;
        float bs = bias[m];
#pragma unroll
        for (int j = 0; j < 4; ++j) {
          int t = N0 + wn * 64 + j * 16 + li;
          out[(size_t)m * 16384 + t] = (_Float16)(acc[i][j][r] + bs);
        }
      }
    }
  }
}

// ---- flash attention v3 -----------------------------------------------------
// grid 512, 4 waves. logical block id XCD-chunked: batch = logical>>6,
// c0 = (logical&63)*32. Wave = (grp = rows grp*16.., wbit = kv/n split half).
// K-tile: hi only, 32 rows x 512 h = 32 KB, double-buffered (gload_lds,
// pre-swizzled source). S = qh*kh + ql*kh. Per-tile: 2 light s_barriers
// (row-max exchange, P visibility) + 1 full syncthreads (stage drain).
__global__ __launch_bounds__(256, 2) void flash_attn(
    const half_t* __restrict__ qs, const half_t* __restrict__ ks,
    const half_t* __restrict__ vt, float* __restrict__ outp) {
  __shared__ half_t kt[2][16384];      // 2 x 32 KB K-hi tiles
  __shared__ half_t plds[2][16][36];   // P per row-group [q16][kv32+pad]
  __shared__ float  tmx[2][2][16];     // row-max partials [grp][wbit][row]
  __shared__ float  lx[2][16];         // final l exchange  [grp][row]

  const int blk0 = blockIdx.x;
  const int logical = (blk0 & 7) * 64 + (blk0 >> 3);   // XCD-chunked (512%8==0)
  const int b  = logical >> 6;
  const int c0 = (logical & 63) * 32;
  const int tid = threadIdx.x;
  const int wv = tid >> 6, lane = tid & 63;
  const int grp = wv >> 1, wbit = wv & 1;
  const int g = lane >> 4, li = lane & 15;
  const int qr0 = c0 + grp * 16;
  const int nh0 = wbit * 256;          // this wave's n-half for PV/output

  const char*   kbytes = (const char*)(ks + (size_t)b * 2048 * 1024);
  const half_t* vb = vt + (size_t)b * 2048;

  // Q fragments in registers: 16 rows, hi + lo (16 chunks each)
  const half_t* qrow = qs + (size_t)(b * 2048 + qr0 + li) * 1024 + 8 * g;
  half8 qh[16], ql[16];
#pragma unroll
  for (int c = 0; c < 16; ++c) {
    qh[c] = *(const half8*)(qrow + c * 32);
    ql[c] = *(const half8*)(qrow + 512 + c * 32);
  }

  const f32x4 kZero = {0.f, 0.f, 0.f, 0.f};
  f32x4 o[16];
#pragma unroll
  for (int i = 0; i < 16; ++i) o[i] = kZero;
  float mr[4] = {-3e38f, -3e38f, -3e38f, -3e38f};  // rows 4g+r (S/D layout)
  float m_li = -3e38f, l_li = 0.f;                 // row li (pa layout)

  // stage K-hi tile: 32 rows x 1024 B; seg -> (row=seg>>6, blk=seg&63),
  // source block pre-XOR'd so LDS stays linear (read applies same XOR).
  auto STAGE = [&](int kv0s, int bufs) {
#pragma unroll
    for (int i2 = 0; i2 < 8; ++i2) {
      int seg = i2 * 256 + tid;
      int r = seg >> 6, bb = seg & 63;
      int bsrc = bb ^ (r & 7);
      gload_lds16(kbytes + (size_t)(kv0s + r) * 2048 + bsrc * 16,
                  (void*)&kt[bufs][seg * 8]);
    }
  };

  STAGE(0, 0);
  __syncthreads();
  int cur = 0;

#pragma unroll 1
  for (int t = 0; t < 64; ++t) {
    const int kv0 = t * 32;
    if (t + 1 < 64) STAGE(kv0 + 32, cur ^ 1);   // prefetch next tile (async)

    // ---- QK: S[16q][16kv(this wave)] = (qh + ql) . kh^T, 4 MFMA chains ----
    const half_t* krow = &kt[cur][(wbit * 16 + li) * 512];
    const int swz = li & 7;
    f32x4 sA = kZero, sB = kZero, sC = kZero, sD = kZero;
#pragma unroll
    for (int c = 0; c < 16; c += 2) {
      half8 k0 = *(const half8*)&krow[((4 * c + g) ^ swz) * 8];
      half8 k1 = *(const half8*)&krow[((4 * c + 4 + g) ^ swz) * 8];
      sA = MFMA16x32(qh[c], k0, sA);
      sC = MFMA16x32(ql[c], k0, sC);
      sB = MFMA16x32(qh[c + 1], k1, sB);
      sD = MFMA16x32(ql[c + 1], k1, sD);
    }
    f32x4 sv = (sA + sC) + (sB + sD);

    // ---- row-max over own 16 kv cols, exchange with partner wave ----
    float tm[4];
#pragma unroll
    for (int r = 0; r < 4; ++r) {
      float v = sv[r];
      v = fmaxf(v, __shfl_xor(v, 1));
      v = fmaxf(v, __shfl_xor(v, 2));
      v = fmaxf(v, __shfl_xor(v, 4));
      v = fmaxf(v, __shfl_xor(v, 8));
      tm[r] = v;
    }
    if (li == 0) {
#pragma unroll
      for (int r = 0; r < 4; ++r) tmx[grp][wbit][4 * g + r] = tm[r];
    }
    asm volatile("s_waitcnt lgkmcnt(0)" ::: "memory");
    __builtin_amdgcn_s_barrier();                 // light: no vmcnt drain

    f32x4 tmo = *(const f32x4*)&tmx[grp][wbit ^ 1][4 * g];
    float tli = fmaxf(tmx[grp][0][li], tmx[grp][1][li]);
    float tf[4];
#pragma unroll
    for (int r = 0; r < 4; ++r) tf[r] = fmaxf(tm[r], tmo[r]);

    // ---- defer-max (THR=8): rescale only when a row max grows past m+8 ----
    int grow = (tf[0] > mr[0] + 8.f) | (tf[1] > mr[1] + 8.f) |
               (tf[2] > mr[2] + 8.f) | (tf[3] > mr[3] + 8.f);
    if (__any(grow)) {
      float al[4];
#pragma unroll
      for (int r = 0; r < 4; ++r) {
        float mn = fmaxf(mr[r], tf[r]);
        al[r] = __expf(mr[r] - mn);
        mr[r] = mn;
      }
      f32x4 av = {al[0], al[1], al[2], al[3]};
#pragma unroll
      for (int i = 0; i < 16; ++i) o[i] *= av;
      float mnli = fmaxf(m_li, tli);
      l_li *= __expf(m_li - mnli);
      m_li = mnli;
    }

    // ---- P = exp(S - m), write to shared P tile (fp16, bounded by e^8) ----
#pragma unroll
    for (int r = 0; r < 4; ++r) {
      float p = __expf(sv[r] - mr[r]);
      plds[grp][4 * g + r][li + 16 * wbit] = (half_t)p;
    }
    asm volatile("s_waitcnt lgkmcnt(0)" ::: "memory");
    __builtin_amdgcn_s_barrier();                 // light: P visible to pair

    // ---- PV over this wave's n-half; l harvested from pa fragment ----
    half8 pa = *(const half8*)&plds[grp][li][8 * g];
    float lp = (float)pa[0] + (float)pa[1] + (float)pa[2] + (float)pa[3] +
               (float)pa[4] + (float)pa[5] + (float)pa[6] + (float)pa[7];
    lp += __shfl_xor(lp, 16);
    lp += __shfl_xor(lp, 32);
    l_li += lp;
#pragma unroll
    for (int ns = 0; ns < 16; ++ns) {
      half8 v0 = *(const half8*)(vb + (size_t)(nh0 + ns * 16 + li) * 16384 + kv0 + 8 * g);
      o[ns] = MFMA16x32(pa, v0, o[ns]);
    }

    __syncthreads();   // drain stage (vmcnt0), protect kt/plds/tmx reuse
    cur ^= 1;
  }

  // ---- final normalization: l is in li-layout, o rows are 4g+r ----
  if (wbit == 0 && g == 0) lx[grp][li] = l_li;
  __syncthreads();
  float inv[4];
#pragma unroll
  for (int r = 0; r < 4; ++r) inv[r] = 1.0f / (lx[grp][4 * g + r] * 22.62741699796952f);

  float* ob = outp + (size_t)b * 1048576 + qr0 + 4 * g;
#pragma unroll
  for (int ns = 0; ns < 16; ++ns) {
#pragma unroll
    for (int r = 0; r < 4; ++r) {
      ob[(size_t)(nh0 + ns * 16 + li) * 2048 + r] = o[ns][r] * inv[r];
    }
  }
}

// ---------------------------------------------------------------------------
extern "C" void kernel_launch(void* const* d_in, const int* in_sizes, int n_in,
                              void* d_out, int out_size, void* d_ws, size_t ws_size,
                              hipStream_t stream) {
  const float* x  = (const float*)d_in[0];
  const float* Wq = (const float*)d_in[1];
  const float* bq = (const float*)d_in[2];
  const float* Wk = (const float*)d_in[3];
  const float* bk = (const float*)d_in[4];
  const float* Wv = (const float*)d_in[5];
  const float* bv = (const float*)d_in[6];

  half_t* xs  = (half_t*)d_ws;                  // [16384][1024]
  half_t* qsb = xs  + (size_t)16384 * 1024;     // [16384][1024]
  half_t* ksb = qsb + (size_t)16384 * 1024;     // [16384][1024]
  half_t* vtb = ksb + (size_t)16384 * 1024;     // [512][16384]
  half_t* wqs = vtb + (size_t)512 * 16384;      // [512][1024]
  half_t* wks = wqs + (size_t)512 * 1024;
  half_t* wvs = wks + (size_t)512 * 1024;

  split_hilo<<<dim3(16384 * 512 / 4 / 256), 256, 0, stream>>>(x, xs, 16384, 512);
  split_hilo<<<dim3(512 * 512 / 4 / 256), 256, 0, stream>>>(Wq, wqs, 512, 512);
  split_hilo<<<dim3(512 * 512 / 4 / 256), 256, 0, stream>>>(Wk, wks, 512, 512);
  split_hilo<<<dim3(512 * 512 / 4 / 256), 256, 0, stream>>>(Wv, wvs, 512, 512);

  proj_gemm<0><<<dim3(128, 4), 256, 0, stream>>>(xs, wqs, bq, qsb);
  proj_gemm<0><<<dim3(128, 4), 256, 0, stream>>>(xs, wks, bk, ksb);
  proj_gemm<1><<<dim3(4, 128), 256, 0, stream>>>(wvs, xs, bv, vtb);

  flash_attn<<<dim3(512), 256, 0, stream>>>(qsb, ksb, vtb, (float*)d_out);
}

// Round 5
// 553.465 us; speedup vs baseline: 1.8230x; 1.1487x over previous
//
#include <hip/hip_runtime.h>

// ---------------------------------------------------------------------------
// Fused QKV-projection + attention (B=8, C=2048, N=512), fp32 in/out.
// Precision: fp32 -> fp16 hi/lo split. Projections: full 3-term fp16 MFMA.
// Attention logits: 2.5-term (qh*kh + ql*kh; qh*kl dropped -> ~6.6e-3 logit
// err, damped by peaked softmax; measured absmax 1.2e-3, threshold 4.6e-3).
// Round 5: RACE FIX. R4's light barriers were asm(waitcnt) + separate
// s_barrier builtin; s_barrier is not a memory op, so the compiler could
// hoist the post-barrier ds_reads (tmx/pa) above it -> pair waves read stale
// partner data under replay timing (post-timing absmax 0.25). Fix: fuse
// "s_waitcnt lgkmcnt(0); s_barrier" into ONE asm with memory clobber, so no
// memory op crosses the barrier either way (vmcnt stays in flight).
// Also: P-tile pad 36->40 halves (16B-aligned half8 rows, <=2-way banks).
// ---------------------------------------------------------------------------

typedef _Float16 half_t;
typedef __attribute__((ext_vector_type(8))) _Float16 half8;
typedef __attribute__((ext_vector_type(4))) _Float16 half4;
typedef __attribute__((ext_vector_type(4))) float    f32x4;

#define MFMA16x32(A_, B_, C_) __builtin_amdgcn_mfma_f32_16x16x32_f16((A_), (B_), (C_), 0, 0, 0)

// barrier that is ALSO a compiler memory fence, without draining vmcnt:
#define LIGHT_BARRIER() asm volatile("s_waitcnt lgkmcnt(0)\n\ts_barrier" ::: "memory")

__device__ __forceinline__ void gload_lds16(const void* g, void* l) {
  __builtin_amdgcn_global_load_lds(
      (const __attribute__((address_space(1))) void*)g,
      (__attribute__((address_space(3))) void*)l, 16, 0, 0);
}

// ---- split fp32 [rows][cols] -> fp16 [rows][2*cols] = [hi | lo] -------------
__global__ void split_hilo(const float* __restrict__ src, half_t* __restrict__ dst,
                           int rows, int cols) {
  int idx = blockIdx.x * 256 + threadIdx.x;
  int total = rows * cols / 4;
  if (idx >= total) return;
  f32x4 v = ((const f32x4*)src)[idx];
  int e = idx * 4;
  int r = e / cols, c = e % cols;
  half4 h, l;
#pragma unroll
  for (int j = 0; j < 4; ++j) {
    float f = v[j];
    _Float16 hh = (_Float16)f;
    h[j] = hh;
    l[j] = (_Float16)(f - (float)hh);
  }
  *(half4*)&dst[(size_t)r * (2 * cols) + c] = h;
  *(half4*)&dst[(size_t)r * (2 * cols) + c + cols] = l;
}

// ---- projection GEMM (unchanged) --------------------------------------------
template <int MODE>
__global__ __launch_bounds__(256) void proj_gemm(
    const half_t* __restrict__ A, const half_t* __restrict__ Bm,
    const float* __restrict__ bias, half_t* __restrict__ out) {
  __shared__ half_t At[128 * 64];
  __shared__ half_t Bt[128 * 64];
  const int tid = threadIdx.x;
  const int lane = tid & 63, wv = tid >> 6;
  const int g = lane >> 4, li = lane & 15;
  const int wm = wv >> 1, wn = wv & 1;
  const int M0 = blockIdx.x * 128, N0 = blockIdx.y * 128;

  const f32x4 kZero = {0.f, 0.f, 0.f, 0.f};
  f32x4 acc[4][4];
#pragma unroll
  for (int i = 0; i < 4; ++i)
#pragma unroll
    for (int j = 0; j < 4; ++j) acc[i][j] = kZero;

  for (int kt = 0; kt < 24; ++kt) {
    const int kc = kt * 64;
    const int ab = kc & 1023;
    const int bb = (kc < 512) ? kc : (kc - 512);
    __syncthreads();
#pragma unroll
    for (int s2 = 0; s2 < 4; ++s2) {
      int bid = tid + 256 * s2;
      int row = bid >> 3, blk = bid & 7;
      half8 va = *(const half8*)&A[(size_t)(M0 + row) * 1024 + ab + blk * 8];
      *(half8*)&At[row * 64 + ((blk ^ (row & 7)) * 8)] = va;
      half8 vb = *(const half8*)&Bm[(size_t)(N0 + row) * 1024 + bb + blk * 8];
      *(half8*)&Bt[row * 64 + ((blk ^ (row & 7)) * 8)] = vb;
    }
    __syncthreads();
#pragma unroll
    for (int kk = 0; kk < 2; ++kk) {
      half8 af[4], bf[4];
#pragma unroll
      for (int i = 0; i < 4; ++i) {
        int ar = wm * 64 + i * 16 + li;
        af[i] = *(const half8*)&At[ar * 64 + (((4 * kk + g) ^ (ar & 7)) * 8)];
        int br = wn * 64 + i * 16 + li;
        bf[i] = *(const half8*)&Bt[br * 64 + (((4 * kk + g) ^ (br & 7)) * 8)];
      }
#pragma unroll
      for (int i = 0; i < 4; ++i)
#pragma unroll
        for (int j = 0; j < 4; ++j) acc[i][j] = MFMA16x32(af[i], bf[j], acc[i][j]);
    }
  }

  if (MODE == 0) {
#pragma unroll
    for (int i = 0; i < 4; ++i) {
      int trow = M0 + wm * 64 + i * 16 + 4 * g;
#pragma unroll
      for (int j = 0; j < 4; ++j) {
        int m = N0 + wn * 64 + j * 16 + li;
        float bs = bias[m];
#pragma unroll
        for (int r = 0; r < 4; ++r) {
          float v = acc[i][j][r] + bs;
          _Float16 hh = (_Float16)v;
          _Float16 ll = (_Float16)(v - (float)hh);
          out[(size_t)(trow + r) * 1024 + m] = hh;
          out[(size_t)(trow + r) * 1024 + m + 512] = ll;
        }
      }
    }
  } else {
#pragma unroll
    for (int i = 0; i < 4; ++i) {
      int m0r = M0 + wm * 64 + i * 16 + 4 * g;
#pragma unroll
      for (int r = 0; r < 4; ++r) {
        int m = m0r + r;
        float bs = bias[m];
#pragma unroll
        for (int j = 0; j < 4; ++j) {
          int t = N0 + wn * 64 + j * 16 + li;
          out[(size_t)m * 16384 + t] = (_Float16)(acc[i][j][r] + bs);
        }
      }
    }
  }
}

// ---- flash attention v5 -----------------------------------------------------
// grid 256 (1 block/CU), 512 threads = 8 waves = 4 pair-groups x 16 q-rows.
// Wave pair: wbit splits kv (QK) and n (PV). K-hi tile (32x512h = 32 KB)
// double-buffered via global_load_lds w/ pre-swizzled source.
// Light fused-asm barriers mid-tile (no vmcnt drain); one full sync per tile.
__global__ __launch_bounds__(512) void flash_attn(
    const half_t* __restrict__ qs, const half_t* __restrict__ ks,
    const half_t* __restrict__ vt, float* __restrict__ outp) {
  __shared__ half_t kt[2][16384];      // 2 x 32 KB K-hi tiles
  __shared__ half_t plds[4][16][40];   // P per pair-group [q16][kv32+pad16B]
  __shared__ float  tmx[4][2][16];     // row-max partials [grp][wbit][row]
  __shared__ float  lx[4][16];         // final l exchange [grp][row]

  const int blk0 = blockIdx.x;
  const int logical = (blk0 & 7) * 32 + (blk0 >> 3);   // XCD-chunked (256%8==0)
  const int b  = logical >> 5;                         // batch = XCD
  const int c0 = (logical & 31) * 64;
  const int tid = threadIdx.x;
  const int wv = tid >> 6, lane = tid & 63;
  const int grp = wv >> 1, wbit = wv & 1;
  const int g = lane >> 4, li = lane & 15;
  const int qr0 = c0 + grp * 16;
  const int nh0 = wbit * 256;          // this wave's n-half for PV/output

  const char*   kbytes = (const char*)(ks + (size_t)b * 2048 * 1024);
  const half_t* vb = vt + (size_t)b * 2048;

  // Q fragments in registers: 16 rows, hi + lo (16 chunks each) = 128 VGPR
  const half_t* qrow = qs + (size_t)(b * 2048 + qr0 + li) * 1024 + 8 * g;
  half8 qh[16], ql[16];
#pragma unroll
  for (int c = 0; c < 16; ++c) {
    qh[c] = *(const half8*)(qrow + c * 32);
    ql[c] = *(const half8*)(qrow + 512 + c * 32);
  }

  const f32x4 kZero = {0.f, 0.f, 0.f, 0.f};
  f32x4 o[16];
#pragma unroll
  for (int i = 0; i < 16; ++i) o[i] = kZero;
  float mr[4] = {-3e38f, -3e38f, -3e38f, -3e38f};  // rows 4g+r (C/D layout)
  float m_li = -3e38f, l_li = 0.f;                 // row li (pa layout)

  // stage K-hi tile: 32 rows x 1024 B = 2048 16B-segs, 4 per thread.
  // LDS linear; source block pre-XOR'd (bb ^ (row&7)); read applies same XOR.
  auto STAGE = [&](int kv0s, int bufs) {
#pragma unroll
    for (int i2 = 0; i2 < 4; ++i2) {
      int seg = i2 * 512 + tid;
      int r = seg >> 6, bb = seg & 63;
      int bsrc = bb ^ (r & 7);
      gload_lds16(kbytes + (size_t)(kv0s + r) * 2048 + bsrc * 16,
                  (void*)&kt[bufs][seg * 8]);
    }
  };

  STAGE(0, 0);
  __syncthreads();
  int cur = 0;

#pragma unroll 1
  for (int t = 0; t < 64; ++t) {
    const int kv0 = t * 32;
    if (t + 1 < 64) STAGE(kv0 + 32, cur ^ 1);   // prefetch next tile (async)

    // ---- QK: S[16q][16kv(this wave)] = (qh + ql) . kh^T, 4 MFMA chains ----
    const half_t* krow = &kt[cur][(wbit * 16 + li) * 512];
    const int swz = li & 7;
    f32x4 sA = kZero, sB = kZero, sC = kZero, sD = kZero;
#pragma unroll
    for (int c = 0; c < 16; c += 2) {
      half8 k0 = *(const half8*)&krow[((4 * c + g) ^ swz) * 8];
      half8 k1 = *(const half8*)&krow[((4 * c + 4 + g) ^ swz) * 8];
      sA = MFMA16x32(qh[c], k0, sA);
      sC = MFMA16x32(ql[c], k0, sC);
      sB = MFMA16x32(qh[c + 1], k1, sB);
      sD = MFMA16x32(ql[c + 1], k1, sD);
    }
    f32x4 sv = (sA + sC) + (sB + sD);

    // ---- row-max over own 16 kv cols, exchange with partner wave ----
    float tm[4];
#pragma unroll
    for (int r = 0; r < 4; ++r) {
      float v = sv[r];
      v = fmaxf(v, __shfl_xor(v, 1));
      v = fmaxf(v, __shfl_xor(v, 2));
      v = fmaxf(v, __shfl_xor(v, 4));
      v = fmaxf(v, __shfl_xor(v, 8));
      tm[r] = v;
    }
    if (li == 0) {
#pragma unroll
      for (int r = 0; r < 4; ++r) tmx[grp][wbit][4 * g + r] = tm[r];
    }
    LIGHT_BARRIER();   // fence+barrier in ONE asm: nothing crosses it

    f32x4 tmo = *(const f32x4*)&tmx[grp][wbit ^ 1][4 * g];
    float tli = fmaxf(tmx[grp][0][li], tmx[grp][1][li]);
    float tf[4];
#pragma unroll
    for (int r = 0; r < 4; ++r) tf[r] = fmaxf(tm[r], tmo[r]);

    // ---- defer-max (THR=8): tf/mr identical across the pair -> consistent ----
    int grow = (tf[0] > mr[0] + 8.f) | (tf[1] > mr[1] + 8.f) |
               (tf[2] > mr[2] + 8.f) | (tf[3] > mr[3] + 8.f);
    if (__any(grow)) {
      float al[4];
#pragma unroll
      for (int r = 0; r < 4; ++r) {
        float mn = fmaxf(mr[r], tf[r]);
        al[r] = __expf(mr[r] - mn);
        mr[r] = mn;
      }
      f32x4 av = {al[0], al[1], al[2], al[3]};
#pragma unroll
      for (int i = 0; i < 16; ++i) o[i] *= av;
      float mnli = fmaxf(m_li, tli);
      l_li *= __expf(m_li - mnli);
      m_li = mnli;
    }

    // ---- P = exp(S - m) -> shared P tile (fp16, bounded by e^8) ----
#pragma unroll
    for (int r = 0; r < 4; ++r) {
      float p = __expf(sv[r] - mr[r]);
      plds[grp][4 * g + r][li + 16 * wbit] = (half_t)p;
    }
    LIGHT_BARRIER();   // P visible to pair; vmcnt (stage) stays in flight

    // ---- PV over this wave's n-half; l harvested from pa fragment ----
    half8 pa = *(const half8*)&plds[grp][li][8 * g];
    float lp = (float)pa[0] + (float)pa[1] + (float)pa[2] + (float)pa[3] +
               (float)pa[4] + (float)pa[5] + (float)pa[6] + (float)pa[7];
    lp += __shfl_xor(lp, 16);
    lp += __shfl_xor(lp, 32);
    l_li += lp;
#pragma unroll
    for (int ns = 0; ns < 16; ++ns) {
      half8 v0 = *(const half8*)(vb + (size_t)(nh0 + ns * 16 + li) * 16384 + kv0 + 8 * g);
      o[ns] = MFMA16x32(pa, v0, o[ns]);
    }

    __syncthreads();   // full fence: drain stage (vmcnt0), protect kt/plds/tmx
    cur ^= 1;
  }

  // ---- final normalization: l in li-layout, o rows are 4g+r ----
  if (wbit == 0 && g == 0) lx[grp][li] = l_li;
  __syncthreads();
  float inv[4];
#pragma unroll
  for (int r = 0; r < 4; ++r) inv[r] = 1.0f / (lx[grp][4 * g + r] * 22.62741699796952f);

  float* ob = outp + (size_t)b * 1048576 + qr0 + 4 * g;
#pragma unroll
  for (int ns = 0; ns < 16; ++ns) {
#pragma unroll
    for (int r = 0; r < 4; ++r) {
      ob[(size_t)(nh0 + ns * 16 + li) * 2048 + r] = o[ns][r] * inv[r];
    }
  }
}

// ---------------------------------------------------------------------------
extern "C" void kernel_launch(void* const* d_in, const int* in_sizes, int n_in,
                              void* d_out, int out_size, void* d_ws, size_t ws_size,
                              hipStream_t stream) {
  const float* x  = (const float*)d_in[0];
  const float* Wq = (const float*)d_in[1];
  const float* bq = (const float*)d_in[2];
  const float* Wk = (const float*)d_in[3];
  const float* bk = (const float*)d_in[4];
  const float* Wv = (const float*)d_in[5];
  const float* bv = (const float*)d_in[6];

  half_t* xs  = (half_t*)d_ws;                  // [16384][1024]
  half_t* qsb = xs  + (size_t)16384 * 1024;     // [16384][1024]
  half_t* ksb = qsb + (size_t)16384 * 1024;     // [16384][1024]
  half_t* vtb = ksb + (size_t)16384 * 1024;     // [512][16384]
  half_t* wqs = vtb + (size_t)512 * 16384;      // [512][1024]
  half_t* wks = wqs + (size_t)512 * 1024;
  half_t* wvs = wks + (size_t)512 * 1024;

  split_hilo<<<dim3(16384 * 512 / 4 / 256), 256, 0, stream>>>(x, xs, 16384, 512);
  split_hilo<<<dim3(512 * 512 / 4 / 256), 256, 0, stream>>>(Wq, wqs, 512, 512);
  split_hilo<<<dim3(512 * 512 / 4 / 256), 256, 0, stream>>>(Wk, wks, 512, 512);
  split_hilo<<<dim3(512 * 512 / 4 / 256), 256, 0, stream>>>(Wv, wvs, 512, 512);

  proj_gemm<0><<<dim3(128, 4), 256, 0, stream>>>(xs, wqs, bq, qsb);
  proj_gemm<0><<<dim3(128, 4), 256, 0, stream>>>(xs, wks, bk, ksb);
  proj_gemm<1><<<dim3(4, 128), 256, 0, stream>>>(wvs, xs, bv, vtb);

  flash_attn<<<dim3(256), 512, 0, stream>>>(qsb, ksb, vtb, (float*)d_out);
}

// Round 6
// 553.430 us; speedup vs baseline: 1.8231x; 1.0001x over previous
//
#include <hip/hip_runtime.h>

// ---------------------------------------------------------------------------
// Fused QKV-projection + attention (B=8, C=2048, N=512), fp32 in/out.
// Precision: fp32 -> fp16 hi/lo split. Projections: full 3-term fp16 MFMA.
// Attention logits: 2.5-term (qh*kh + ql*kh; qh*kl dropped -> ~6.6e-3 logit
// err, damped by peaked softmax; measured absmax 1.2e-3, threshold 4.6e-3).
// Round 6: REGISTER RESIDENCY FIX. R5 profiled at VGPR_Count=128 — the
// compiler's occupancy heuristic (LDS 70KB -> could fit 2 blocks/CU -> target
// 4 waves/EU -> 128-VGPR budget) made it re-load the Q fragments from global
// EVERY tile (~8.6 GB of L2 traffic ≈ 19.5 TB/s = the whole 442 us) plus
// ~8 MB scratch spill writes. Fix: amdgpu_waves_per_eu(2,2) pins target
// occupancy at 2 waves/EU -> allocator budget 256 VGPR -> Q (128) + O (64)
// stay register-resident, no remat, no spills. Everything else unchanged.
// ---------------------------------------------------------------------------

typedef _Float16 half_t;
typedef __attribute__((ext_vector_type(8))) _Float16 half8;
typedef __attribute__((ext_vector_type(4))) _Float16 half4;
typedef __attribute__((ext_vector_type(4))) float    f32x4;

#define MFMA16x32(A_, B_, C_) __builtin_amdgcn_mfma_f32_16x16x32_f16((A_), (B_), (C_), 0, 0, 0)

// barrier that is ALSO a compiler memory fence, without draining vmcnt:
#define LIGHT_BARRIER() asm volatile("s_waitcnt lgkmcnt(0)\n\ts_barrier" ::: "memory")

__device__ __forceinline__ void gload_lds16(const void* g, void* l) {
  __builtin_amdgcn_global_load_lds(
      (const __attribute__((address_space(1))) void*)g,
      (__attribute__((address_space(3))) void*)l, 16, 0, 0);
}

// ---- split fp32 [rows][cols] -> fp16 [rows][2*cols] = [hi | lo] -------------
__global__ void split_hilo(const float* __restrict__ src, half_t* __restrict__ dst,
                           int rows, int cols) {
  int idx = blockIdx.x * 256 + threadIdx.x;
  int total = rows * cols / 4;
  if (idx >= total) return;
  f32x4 v = ((const f32x4*)src)[idx];
  int e = idx * 4;
  int r = e / cols, c = e % cols;
  half4 h, l;
#pragma unroll
  for (int j = 0; j < 4; ++j) {
    float f = v[j];
    _Float16 hh = (_Float16)f;
    h[j] = hh;
    l[j] = (_Float16)(f - (float)hh);
  }
  *(half4*)&dst[(size_t)r * (2 * cols) + c] = h;
  *(half4*)&dst[(size_t)r * (2 * cols) + c + cols] = l;
}

// ---- projection GEMM (unchanged) --------------------------------------------
template <int MODE>
__global__ __launch_bounds__(256) void proj_gemm(
    const half_t* __restrict__ A, const half_t* __restrict__ Bm,
    const float* __restrict__ bias, half_t* __restrict__ out) {
  __shared__ half_t At[128 * 64];
  __shared__ half_t Bt[128 * 64];
  const int tid = threadIdx.x;
  const int lane = tid & 63, wv = tid >> 6;
  const int g = lane >> 4, li = lane & 15;
  const int wm = wv >> 1, wn = wv & 1;
  const int M0 = blockIdx.x * 128, N0 = blockIdx.y * 128;

  const f32x4 kZero = {0.f, 0.f, 0.f, 0.f};
  f32x4 acc[4][4];
#pragma unroll
  for (int i = 0; i < 4; ++i)
#pragma unroll
    for (int j = 0; j < 4; ++j) acc[i][j] = kZero;

  for (int kt = 0; kt < 24; ++kt) {
    const int kc = kt * 64;
    const int ab = kc & 1023;
    const int bb = (kc < 512) ? kc : (kc - 512);
    __syncthreads();
#pragma unroll
    for (int s2 = 0; s2 < 4; ++s2) {
      int bid = tid + 256 * s2;
      int row = bid >> 3, blk = bid & 7;
      half8 va = *(const half8*)&A[(size_t)(M0 + row) * 1024 + ab + blk * 8];
      *(half8*)&At[row * 64 + ((blk ^ (row & 7)) * 8)] = va;
      half8 vb = *(const half8*)&Bm[(size_t)(N0 + row) * 1024 + bb + blk * 8];
      *(half8*)&Bt[row * 64 + ((blk ^ (row & 7)) * 8)] = vb;
    }
    __syncthreads();
#pragma unroll
    for (int kk = 0; kk < 2; ++kk) {
      half8 af[4], bf[4];
#pragma unroll
      for (int i = 0; i < 4; ++i) {
        int ar = wm * 64 + i * 16 + li;
        af[i] = *(const half8*)&At[ar * 64 + (((4 * kk + g) ^ (ar & 7)) * 8)];
        int br = wn * 64 + i * 16 + li;
        bf[i] = *(const half8*)&Bt[br * 64 + (((4 * kk + g) ^ (br & 7)) * 8)];
      }
#pragma unroll
      for (int i = 0; i < 4; ++i)
#pragma unroll
        for (int j = 0; j < 4; ++j) acc[i][j] = MFMA16x32(af[i], bf[j], acc[i][j]);
    }
  }

  if (MODE == 0) {
#pragma unroll
    for (int i = 0; i < 4; ++i) {
      int trow = M0 + wm * 64 + i * 16 + 4 * g;
#pragma unroll
      for (int j = 0; j < 4; ++j) {
        int m = N0 + wn * 64 + j * 16 + li;
        float bs = bias[m];
#pragma unroll
        for (int r = 0; r < 4; ++r) {
          float v = acc[i][j][r] + bs;
          _Float16 hh = (_Float16)v;
          _Float16 ll = (_Float16)(v - (float)hh);
          out[(size_t)(trow + r) * 1024 + m] = hh;
          out[(size_t)(trow + r) * 1024 + m + 512] = ll;
        }
      }
    }
  } else {
#pragma unroll
    for (int i = 0; i < 4; ++i) {
      int m0r = M0 + wm * 64 + i * 16 + 4 * g;
#pragma unroll
      for (int r = 0; r < 4; ++r) {
        int m = m0r + r;
        float bs = bias[m];
#pragma unroll
        for (int j = 0; j < 4; ++j) {
          int t = N0 + wn * 64 + j * 16 + li;
          out[(size_t)m * 16384 + t] = (_Float16)(acc[i][j][r] + bs);
        }
      }
    }
  }
}

// ---- flash attention v6 -----------------------------------------------------
// grid 256 (1 block/CU), 512 threads = 8 waves = 4 pair-groups x 16 q-rows.
// Wave pair: wbit splits kv (QK) and n (PV). K-hi tile (32x512h = 32 KB)
// double-buffered via global_load_lds w/ pre-swizzled source.
// amdgpu_waves_per_eu(2,2): pin occupancy target -> 256-VGPR budget -> Q/O
// register-resident (this was the whole R5 bottleneck).
__global__ __attribute__((amdgpu_flat_work_group_size(512, 512),
                          amdgpu_waves_per_eu(2, 2))) void flash_attn(
    const half_t* __restrict__ qs, const half_t* __restrict__ ks,
    const half_t* __restrict__ vt, float* __restrict__ outp) {
  __shared__ half_t kt[2][16384];      // 2 x 32 KB K-hi tiles
  __shared__ half_t plds[4][16][40];   // P per pair-group [q16][kv32+pad16B]
  __shared__ float  tmx[4][2][16];     // row-max partials [grp][wbit][row]
  __shared__ float  lx[4][16];         // final l exchange [grp][row]

  const int blk0 = blockIdx.x;
  const int logical = (blk0 & 7) * 32 + (blk0 >> 3);   // XCD-chunked (256%8==0)
  const int b  = logical >> 5;                         // batch = XCD
  const int c0 = (logical & 31) * 64;
  const int tid = threadIdx.x;
  const int wv = tid >> 6, lane = tid & 63;
  const int grp = wv >> 1, wbit = wv & 1;
  const int g = lane >> 4, li = lane & 15;
  const int qr0 = c0 + grp * 16;
  const int nh0 = wbit * 256;          // this wave's n-half for PV/output

  const char*   kbytes = (const char*)(ks + (size_t)b * 2048 * 1024);
  const half_t* vb = vt + (size_t)b * 2048;

  // Q fragments in registers: 16 rows, hi + lo (16 chunks each) = 128 VGPR
  const half_t* qrow = qs + (size_t)(b * 2048 + qr0 + li) * 1024 + 8 * g;
  half8 qh[16], ql[16];
#pragma unroll
  for (int c = 0; c < 16; ++c) {
    qh[c] = *(const half8*)(qrow + c * 32);
    ql[c] = *(const half8*)(qrow + 512 + c * 32);
  }

  const f32x4 kZero = {0.f, 0.f, 0.f, 0.f};
  f32x4 o[16];
#pragma unroll
  for (int i = 0; i < 16; ++i) o[i] = kZero;
  float mr[4] = {-3e38f, -3e38f, -3e38f, -3e38f};  // rows 4g+r (C/D layout)
  float m_li = -3e38f, l_li = 0.f;                 // row li (pa layout)

  // stage K-hi tile: 32 rows x 1024 B = 2048 16B-segs, 4 per thread.
  // LDS linear; source block pre-XOR'd (bb ^ (row&7)); read applies same XOR.
  auto STAGE = [&](int kv0s, int bufs) {
#pragma unroll
    for (int i2 = 0; i2 < 4; ++i2) {
      int seg = i2 * 512 + tid;
      int r = seg >> 6, bb = seg & 63;
      int bsrc = bb ^ (r & 7);
      gload_lds16(kbytes + (size_t)(kv0s + r) * 2048 + bsrc * 16,
                  (void*)&kt[bufs][seg * 8]);
    }
  };

  STAGE(0, 0);
  __syncthreads();
  int cur = 0;

#pragma unroll 1
  for (int t = 0; t < 64; ++t) {
    const int kv0 = t * 32;
    if (t + 1 < 64) STAGE(kv0 + 32, cur ^ 1);   // prefetch next tile (async)

    // ---- QK: S[16q][16kv(this wave)] = (qh + ql) . kh^T, 4 MFMA chains ----
    const half_t* krow = &kt[cur][(wbit * 16 + li) * 512];
    const int swz = li & 7;
    f32x4 sA = kZero, sB = kZero, sC = kZero, sD = kZero;
#pragma unroll
    for (int c = 0; c < 16; c += 2) {
      half8 k0 = *(const half8*)&krow[((4 * c + g) ^ swz) * 8];
      half8 k1 = *(const half8*)&krow[((4 * c + 4 + g) ^ swz) * 8];
      sA = MFMA16x32(qh[c], k0, sA);
      sC = MFMA16x32(ql[c], k0, sC);
      sB = MFMA16x32(qh[c + 1], k1, sB);
      sD = MFMA16x32(ql[c + 1], k1, sD);
    }
    f32x4 sv = (sA + sC) + (sB + sD);

    // ---- row-max over own 16 kv cols, exchange with partner wave ----
    float tm[4];
#pragma unroll
    for (int r = 0; r < 4; ++r) {
      float v = sv[r];
      v = fmaxf(v, __shfl_xor(v, 1));
      v = fmaxf(v, __shfl_xor(v, 2));
      v = fmaxf(v, __shfl_xor(v, 4));
      v = fmaxf(v, __shfl_xor(v, 8));
      tm[r] = v;
    }
    if (li == 0) {
#pragma unroll
      for (int r = 0; r < 4; ++r) tmx[grp][wbit][4 * g + r] = tm[r];
    }
    LIGHT_BARRIER();   // fence+barrier in ONE asm: nothing crosses it

    f32x4 tmo = *(const f32x4*)&tmx[grp][wbit ^ 1][4 * g];
    float tli = fmaxf(tmx[grp][0][li], tmx[grp][1][li]);
    float tf[4];
#pragma unroll
    for (int r = 0; r < 4; ++r) tf[r] = fmaxf(tm[r], tmo[r]);

    // ---- defer-max (THR=8): tf/mr identical across the pair -> consistent ----
    int grow = (tf[0] > mr[0] + 8.f) | (tf[1] > mr[1] + 8.f) |
               (tf[2] > mr[2] + 8.f) | (tf[3] > mr[3] + 8.f);
    if (__any(grow)) {
      float al[4];
#pragma unroll
      for (int r = 0; r < 4; ++r) {
        float mn = fmaxf(mr[r], tf[r]);
        al[r] = __expf(mr[r] - mn);
        mr[r] = mn;
      }
      f32x4 av = {al[0], al[1], al[2], al[3]};
#pragma unroll
      for (int i = 0; i < 16; ++i) o[i] *= av;
      float mnli = fmaxf(m_li, tli);
      l_li *= __expf(m_li - mnli);
      m_li = mnli;
    }

    // ---- P = exp(S - m) -> shared P tile (fp16, bounded by e^8) ----
#pragma unroll
    for (int r = 0; r < 4; ++r) {
      float p = __expf(sv[r] - mr[r]);
      plds[grp][4 * g + r][li + 16 * wbit] = (half_t)p;
    }
    LIGHT_BARRIER();   // P visible to pair; vmcnt (stage) stays in flight

    // ---- PV over this wave's n-half; l harvested from pa fragment ----
    half8 pa = *(const half8*)&plds[grp][li][8 * g];
    float lp = (float)pa[0] + (float)pa[1] + (float)pa[2] + (float)pa[3] +
               (float)pa[4] + (float)pa[5] + (float)pa[6] + (float)pa[7];
    lp += __shfl_xor(lp, 16);
    lp += __shfl_xor(lp, 32);
    l_li += lp;
#pragma unroll
    for (int ns = 0; ns < 16; ++ns) {
      half8 v0 = *(const half8*)(vb + (size_t)(nh0 + ns * 16 + li) * 16384 + kv0 + 8 * g);
      o[ns] = MFMA16x32(pa, v0, o[ns]);
    }

    __syncthreads();   // full fence: drain stage (vmcnt0), protect kt/plds/tmx
    cur ^= 1;
  }

  // ---- final normalization: l in li-layout, o rows are 4g+r ----
  if (wbit == 0 && g == 0) lx[grp][li] = l_li;
  __syncthreads();
  float inv[4];
#pragma unroll
  for (int r = 0; r < 4; ++r) inv[r] = 1.0f / (lx[grp][4 * g + r] * 22.62741699796952f);

  float* ob = outp + (size_t)b * 1048576 + qr0 + 4 * g;
#pragma unroll
  for (int ns = 0; ns < 16; ++ns) {
#pragma unroll
    for (int r = 0; r < 4; ++r) {
      ob[(size_t)(nh0 + ns * 16 + li) * 2048 + r] = o[ns][r] * inv[r];
    }
  }
}

// ---------------------------------------------------------------------------
extern "C" void kernel_launch(void* const* d_in, const int* in_sizes, int n_in,
                              void* d_out, int out_size, void* d_ws, size_t ws_size,
                              hipStream_t stream) {
  const float* x  = (const float*)d_in[0];
  const float* Wq = (const float*)d_in[1];
  const float* bq = (const float*)d_in[2];
  const float* Wk = (const float*)d_in[3];
  const float* bk = (const float*)d_in[4];
  const float* Wv = (const float*)d_in[5];
  const float* bv = (const float*)d_in[6];

  half_t* xs  = (half_t*)d_ws;                  // [16384][1024]
  half_t* qsb = xs  + (size_t)16384 * 1024;     // [16384][1024]
  half_t* ksb = qsb + (size_t)16384 * 1024;     // [16384][1024]
  half_t* vtb = ksb + (size_t)16384 * 1024;     // [512][16384]
  half_t* wqs = vtb + (size_t)512 * 16384;      // [512][1024]
  half_t* wks = wqs + (size_t)512 * 1024;
  half_t* wvs = wks + (size_t)512 * 1024;

  split_hilo<<<dim3(16384 * 512 / 4 / 256), 256, 0, stream>>>(x, xs, 16384, 512);
  split_hilo<<<dim3(512 * 512 / 4 / 256), 256, 0, stream>>>(Wq, wqs, 512, 512);
  split_hilo<<<dim3(512 * 512 / 4 / 256), 256, 0, stream>>>(Wk, wks, 512, 512);
  split_hilo<<<dim3(512 * 512 / 4 / 256), 256, 0, stream>>>(Wv, wvs, 512, 512);

  proj_gemm<0><<<dim3(128, 4), 256, 0, stream>>>(xs, wqs, bq, qsb);
  proj_gemm<0><<<dim3(128, 4), 256, 0, stream>>>(xs, wks, bk, ksb);
  proj_gemm<1><<<dim3(4, 128), 256, 0, stream>>>(wvs, xs, bv, vtb);

  flash_attn<<<dim3(256), 512, 0, stream>>>(qsb, ksb, vtb, (float*)d_out);
}

// Round 7
// 518.553 us; speedup vs baseline: 1.9457x; 1.0673x over previous
//
#include <hip/hip_runtime.h>

// ---------------------------------------------------------------------------
// Fused QKV-projection + attention (B=8, C=2048, N=512), fp32 in/out.
// Precision: fp32 -> fp16 hi/lo split. Projections: full 3-term fp16 MFMA.
// Attention logits: 2.5-term (qh*kh + ql*kh; qh*kl dropped -> absmax 1.2e-3
// measured, threshold 4.6e-3).
// Round 7: (1) Q pinned in registers via volatile-asm global loads (compiler
// cannot remat/reload them -> the suspected R5/R6 per-tile Q refetch dies);
// (2) V stored kv-blocked (vblk[token>>5][n][token&31]) so PV loads are one
// contiguous 1KB burst per instruction instead of 16 scattered 64B lines;
// (3) softmax row-max via DPP rotate-reduce (VALU, off the DS pipe) and
// single-barrier tile: P stored normalized by own-half max, pa rescaled by
// exp(tm_half - m_joint) after ONE light barrier (defer-max THR=8 kept).
// ---------------------------------------------------------------------------

typedef _Float16 half_t;
typedef __attribute__((ext_vector_type(8))) _Float16 half8;
typedef __attribute__((ext_vector_type(4))) _Float16 half4;
typedef __attribute__((ext_vector_type(4))) float    f32x4;

#define MFMA16x32(A_, B_, C_) __builtin_amdgcn_mfma_f32_16x16x32_f16((A_), (B_), (C_), 0, 0, 0)

// barrier that is ALSO a compiler memory fence, without draining vmcnt:
#define LIGHT_BARRIER() asm volatile("s_waitcnt lgkmcnt(0)\n\ts_barrier" ::: "memory")

__device__ __forceinline__ void gload_lds16(const void* g, void* l) {
  __builtin_amdgcn_global_load_lds(
      (const __attribute__((address_space(1))) void*)g,
      (__attribute__((address_space(3))) void*)l, 16, 0, 0);
}

// max-reduce over each 16-lane row via DPP (quad_perm xor1/xor2, row_ror 4/8).
__device__ __forceinline__ float dpp_max16(float x) {
  int t;
  t = __builtin_amdgcn_update_dpp(__float_as_int(x), __float_as_int(x), 0xB1, 0xF, 0xF, false);
  x = fmaxf(x, __int_as_float(t));
  t = __builtin_amdgcn_update_dpp(__float_as_int(x), __float_as_int(x), 0x4E, 0xF, 0xF, false);
  x = fmaxf(x, __int_as_float(t));
  t = __builtin_amdgcn_update_dpp(__float_as_int(x), __float_as_int(x), 0x124, 0xF, 0xF, false);
  x = fmaxf(x, __int_as_float(t));
  t = __builtin_amdgcn_update_dpp(__float_as_int(x), __float_as_int(x), 0x128, 0xF, 0xF, false);
  x = fmaxf(x, __int_as_float(t));
  return x;
}

// ---- split fp32 [rows][cols] -> fp16 [rows][2*cols] = [hi | lo] -------------
__global__ void split_hilo(const float* __restrict__ src, half_t* __restrict__ dst,
                           int rows, int cols) {
  int idx = blockIdx.x * 256 + threadIdx.x;
  int total = rows * cols / 4;
  if (idx >= total) return;
  f32x4 v = ((const f32x4*)src)[idx];
  int e = idx * 4;
  int r = e / cols, c = e % cols;
  half4 h, l;
#pragma unroll
  for (int j = 0; j < 4; ++j) {
    float f = v[j];
    _Float16 hh = (_Float16)f;
    h[j] = hh;
    l[j] = (_Float16)(f - (float)hh);
  }
  *(half4*)&dst[(size_t)r * (2 * cols) + c] = h;
  *(half4*)&dst[(size_t)r * (2 * cols) + c + cols] = l;
}

// ---- projection GEMM --------------------------------------------------------
// MODE 0: out[t][m]=hi, out[t][m+512]=lo   (q/k)
// MODE 1: out[(t>>5)*16384 + m*32 + (t&31)] = f16(val)  (v kv-blocked)
template <int MODE>
__global__ __launch_bounds__(256) void proj_gemm(
    const half_t* __restrict__ A, const half_t* __restrict__ Bm,
    const float* __restrict__ bias, half_t* __restrict__ out) {
  __shared__ half_t At[128 * 64];
  __shared__ half_t Bt[128 * 64];
  const int tid = threadIdx.x;
  const int lane = tid & 63, wv = tid >> 6;
  const int g = lane >> 4, li = lane & 15;
  const int wm = wv >> 1, wn = wv & 1;
  const int M0 = blockIdx.x * 128, N0 = blockIdx.y * 128;

  const f32x4 kZero = {0.f, 0.f, 0.f, 0.f};
  f32x4 acc[4][4];
#pragma unroll
  for (int i = 0; i < 4; ++i)
#pragma unroll
    for (int j = 0; j < 4; ++j) acc[i][j] = kZero;

  for (int kt = 0; kt < 24; ++kt) {
    const int kc = kt * 64;
    const int ab = kc & 1023;
    const int bb = (kc < 512) ? kc : (kc - 512);
    __syncthreads();
#pragma unroll
    for (int s2 = 0; s2 < 4; ++s2) {
      int bid = tid + 256 * s2;
      int row = bid >> 3, blk = bid & 7;
      half8 va = *(const half8*)&A[(size_t)(M0 + row) * 1024 + ab + blk * 8];
      *(half8*)&At[row * 64 + ((blk ^ (row & 7)) * 8)] = va;
      half8 vb = *(const half8*)&Bm[(size_t)(N0 + row) * 1024 + bb + blk * 8];
      *(half8*)&Bt[row * 64 + ((blk ^ (row & 7)) * 8)] = vb;
    }
    __syncthreads();
#pragma unroll
    for (int kk = 0; kk < 2; ++kk) {
      half8 af[4], bf[4];
#pragma unroll
      for (int i = 0; i < 4; ++i) {
        int ar = wm * 64 + i * 16 + li;
        af[i] = *(const half8*)&At[ar * 64 + (((4 * kk + g) ^ (ar & 7)) * 8)];
        int br = wn * 64 + i * 16 + li;
        bf[i] = *(const half8*)&Bt[br * 64 + (((4 * kk + g) ^ (br & 7)) * 8)];
      }
#pragma unroll
      for (int i = 0; i < 4; ++i)
#pragma unroll
        for (int j = 0; j < 4; ++j) acc[i][j] = MFMA16x32(af[i], bf[j], acc[i][j]);
    }
  }

  if (MODE == 0) {
#pragma unroll
    for (int i = 0; i < 4; ++i) {
      int trow = M0 + wm * 64 + i * 16 + 4 * g;
#pragma unroll
      for (int j = 0; j < 4; ++j) {
        int m = N0 + wn * 64 + j * 16 + li;
        float bs = bias[m];
#pragma unroll
        for (int r = 0; r < 4; ++r) {
          float v = acc[i][j][r] + bs;
          _Float16 hh = (_Float16)v;
          _Float16 ll = (_Float16)(v - (float)hh);
          out[(size_t)(trow + r) * 1024 + m] = hh;
          out[(size_t)(trow + r) * 1024 + m + 512] = ll;
        }
      }
    }
  } else {
#pragma unroll
    for (int i = 0; i < 4; ++i) {
      int m0r = M0 + wm * 64 + i * 16 + 4 * g;
#pragma unroll
      for (int r = 0; r < 4; ++r) {
        int m = m0r + r;
        float bs = bias[m];
#pragma unroll
        for (int j = 0; j < 4; ++j) {
          int tt = N0 + wn * 64 + j * 16 + li;
          out[(size_t)(tt >> 5) * 16384 + (size_t)m * 32 + (tt & 31)] =
              (_Float16)(acc[i][j][r] + bs);
        }
      }
    }
  }
}

// ---- flash attention v7 -----------------------------------------------------
// grid 256 (1 block/CU), 512 threads = 8 waves = 4 pair-groups x 16 q-rows.
// Wave pair: wbit splits kv (QK) and n (PV). K-hi tile double-buffered via
// global_load_lds. Q pinned via volatile asm loads. V kv-blocked (coalesced).
// One light barrier per tile: P = exp(s - tm_half) stored immediately; pa
// rescaled by exp(tm_half - m_joint) after the max exchange.
__global__ __attribute__((amdgpu_flat_work_group_size(512, 512),
                          amdgpu_waves_per_eu(2, 2))) void flash_attn(
    const half_t* __restrict__ qs, const half_t* __restrict__ ks,
    const half_t* __restrict__ vblk, float* __restrict__ outp) {
  __shared__ half_t kt[2][16384];      // 2 x 32 KB K-hi tiles
  __shared__ half_t plds[4][16][40];   // P per pair-group [q16][kv32+pad16B]
  __shared__ float  tmx[4][2][16];     // per-tile half row-max [grp][wbit][row]
  __shared__ float  lx[4][16];         // final l exchange [grp][row]

  const int blk0 = blockIdx.x;
  const int logical = (blk0 & 7) * 32 + (blk0 >> 3);   // XCD-chunked (256%8==0)
  const int b  = logical >> 5;                         // batch = XCD
  const int c0 = (logical & 31) * 64;
  const int tid = threadIdx.x;
  const int wv = tid >> 6, lane = tid & 63;
  const int grp = wv >> 1, wbit = wv & 1;
  const int g = lane >> 4, li = lane & 15;
  const int qr0 = c0 + grp * 16;
  const int nh0 = wbit * 256;          // this wave's n-half for PV/output

  const char*   kbytes = (const char*)(ks + (size_t)b * 2048 * 1024);

  // Q fragments pinned in registers via volatile asm (cannot be remat'd):
  // 16 rows, hi + lo (16 chunks each) = 128 VGPR.
  const half_t* qrow = qs + (size_t)(b * 2048 + qr0 + li) * 1024 + 8 * g;
  half8 qh[16], ql[16];
#pragma unroll
  for (int c = 0; c < 16; ++c) {
    const half_t* ah = qrow + c * 32;
    const half_t* al = qrow + 512 + c * 32;
    asm volatile("global_load_dwordx4 %0, %1, off" : "=v"(qh[c]) : "v"(ah));
    asm volatile("global_load_dwordx4 %0, %1, off" : "=v"(ql[c]) : "v"(al));
  }
  asm volatile("s_waitcnt vmcnt(0)" ::: "memory");

  const f32x4 kZero = {0.f, 0.f, 0.f, 0.f};
  f32x4 o[16];
#pragma unroll
  for (int i = 0; i < 16; ++i) o[i] = kZero;
  float mr[4] = {-3e38f, -3e38f, -3e38f, -3e38f};  // joint running max, rows 4g+r
  float m_li = -3e38f, l_li = 0.f;                 // joint running max/l, row li

  // stage K-hi tile: 32 rows x 1024 B = 2048 16B-segs, 4 per thread.
  auto STAGE = [&](int kv0s, int bufs) {
#pragma unroll
    for (int i2 = 0; i2 < 4; ++i2) {
      int seg = i2 * 512 + tid;
      int r = seg >> 6, bb = seg & 63;
      int bsrc = bb ^ (r & 7);
      gload_lds16(kbytes + (size_t)(kv0s + r) * 2048 + bsrc * 16,
                  (void*)&kt[bufs][seg * 8]);
    }
  };

  STAGE(0, 0);
  __syncthreads();
  int cur = 0;

#pragma unroll 1
  for (int t = 0; t < 64; ++t) {
    if (t + 1 < 64) STAGE((t + 1) * 32, cur ^ 1);   // prefetch next tile (async)

    // ---- QK: S[16q][16kv(this wave)] = (qh + ql) . kh^T, 4 MFMA chains ----
    const half_t* krow = &kt[cur][(wbit * 16 + li) * 512];
    const int swz = li & 7;
    f32x4 sA = kZero, sB = kZero, sC = kZero, sD = kZero;
#pragma unroll
    for (int c = 0; c < 16; c += 2) {
      half8 k0 = *(const half8*)&krow[((4 * c + g) ^ swz) * 8];
      half8 k1 = *(const half8*)&krow[((4 * c + 4 + g) ^ swz) * 8];
      sA = MFMA16x32(qh[c], k0, sA);
      sC = MFMA16x32(ql[c], k0, sC);
      sB = MFMA16x32(qh[c + 1], k1, sB);
      sD = MFMA16x32(ql[c + 1], k1, sD);
    }
    f32x4 sv = (sA + sC) + (sB + sD);

    // ---- per-row max of THIS half (DPP, pure VALU); P normalized by it ----
    float tm[4];
#pragma unroll
    for (int r = 0; r < 4; ++r) tm[r] = dpp_max16(sv[r]);
#pragma unroll
    for (int r = 0; r < 4; ++r) {
      float p = __expf(sv[r] - tm[r]);            // <= 1
      plds[grp][4 * g + r][li + 16 * wbit] = (half_t)p;
    }
    if (li == 0) {
#pragma unroll
      for (int r = 0; r < 4; ++r) tmx[grp][wbit][4 * g + r] = tm[r];
    }
    LIGHT_BARRIER();   // single exchange point: P + half-maxes visible

    // ---- joint max, defer-max (THR=8), pa rescale ----
    f32x4 t0 = *(const f32x4*)&tmx[grp][0][4 * g];
    f32x4 t1 = *(const f32x4*)&tmx[grp][1][4 * g];
    float tA = tmx[grp][0][li], tB = tmx[grp][1][li];
    float tf[4];
#pragma unroll
    for (int r = 0; r < 4; ++r) tf[r] = fmaxf(t0[r], t1[r]);
    int grow = (tf[0] > mr[0] + 8.f) | (tf[1] > mr[1] + 8.f) |
               (tf[2] > mr[2] + 8.f) | (tf[3] > mr[3] + 8.f);
    if (__any(grow)) {
      float al[4];
#pragma unroll
      for (int r = 0; r < 4; ++r) {
        float mn = fmaxf(mr[r], tf[r]);
        al[r] = __expf(mr[r] - mn);
        mr[r] = mn;
      }
      f32x4 av = {al[0], al[1], al[2], al[3]};
#pragma unroll
      for (int i = 0; i < 16; ++i) o[i] *= av;
      float mnli = fmaxf(m_li, fmaxf(tA, tB));
      l_li *= __expf(m_li - mnli);
      m_li = mnli;
    }
    // scale for this lane's pa fragment (cols 8g..8g+7 live in half g>>1):
    float sh = __expf(((g < 2) ? tA : tB) - m_li);   // <= e^8 (defer bound)
    half_t sh16 = (half_t)sh;
    half8 pa = *(const half8*)&plds[grp][li][8 * g];
#pragma unroll
    for (int e = 0; e < 8; ++e) pa[e] = pa[e] * sh16;

    // l harvested from the scaled pa fragment
    float lp = 0.f;
#pragma unroll
    for (int e = 0; e < 8; ++e) lp += (float)pa[e];
    lp += __shfl_xor(lp, 16);
    lp += __shfl_xor(lp, 32);
    l_li += lp;

    // ---- PV over this wave's n-half; V kv-blocked -> 1KB coalesced loads ----
    const half_t* vtile = vblk + ((size_t)(b * 64 + t)) * 16384 +
                          (size_t)nh0 * 32 + li * 32 + 8 * g;
#pragma unroll
    for (int ns = 0; ns < 16; ++ns) {
      half8 v0 = *(const half8*)(vtile + ns * 512);
      o[ns] = MFMA16x32(pa, v0, o[ns]);
    }

    __syncthreads();   // full fence: drain stage (vmcnt0), protect kt/plds/tmx
    cur ^= 1;
  }

  // ---- final normalization: l in li-layout, o rows are 4g+r ----
  if (wbit == 0 && g == 0) lx[grp][li] = l_li;
  __syncthreads();
  float inv[4];
#pragma unroll
  for (int r = 0; r < 4; ++r) inv[r] = 1.0f / (lx[grp][4 * g + r] * 22.62741699796952f);

  float* ob = outp + (size_t)b * 1048576 + qr0 + 4 * g;
#pragma unroll
  for (int ns = 0; ns < 16; ++ns) {
#pragma unroll
    for (int r = 0; r < 4; ++r) {
      ob[(size_t)(nh0 + ns * 16 + li) * 2048 + r] = o[ns][r] * inv[r];
    }
  }
}

// ---------------------------------------------------------------------------
extern "C" void kernel_launch(void* const* d_in, const int* in_sizes, int n_in,
                              void* d_out, int out_size, void* d_ws, size_t ws_size,
                              hipStream_t stream) {
  const float* x  = (const float*)d_in[0];
  const float* Wq = (const float*)d_in[1];
  const float* bq = (const float*)d_in[2];
  const float* Wk = (const float*)d_in[3];
  const float* bk = (const float*)d_in[4];
  const float* Wv = (const float*)d_in[5];
  const float* bv = (const float*)d_in[6];

  half_t* xs  = (half_t*)d_ws;                  // [16384][1024]
  half_t* qsb = xs  + (size_t)16384 * 1024;     // [16384][1024]
  half_t* ksb = qsb + (size_t)16384 * 1024;     // [16384][1024]
  half_t* vtb = ksb + (size_t)16384 * 1024;     // [512 blk][512 n][32 kv]
  half_t* wqs = vtb + (size_t)512 * 16384;      // [512][1024]
  half_t* wks = wqs + (size_t)512 * 1024;
  half_t* wvs = wks + (size_t)512 * 1024;

  split_hilo<<<dim3(16384 * 512 / 4 / 256), 256, 0, stream>>>(x, xs, 16384, 512);
  split_hilo<<<dim3(512 * 512 / 4 / 256), 256, 0, stream>>>(Wq, wqs, 512, 512);
  split_hilo<<<dim3(512 * 512 / 4 / 256), 256, 0, stream>>>(Wk, wks, 512, 512);
  split_hilo<<<dim3(512 * 512 / 4 / 256), 256, 0, stream>>>(Wv, wvs, 512, 512);

  proj_gemm<0><<<dim3(128, 4), 256, 0, stream>>>(xs, wqs, bq, qsb);
  proj_gemm<0><<<dim3(128, 4), 256, 0, stream>>>(xs, wks, bk, ksb);
  proj_gemm<1><<<dim3(4, 128), 256, 0, stream>>>(wvs, xs, bv, vtb);

  flash_attn<<<dim3(256), 512, 0, stream>>>(qsb, ksb, vtb, (float*)d_out);
}

// Round 8
// 513.678 us; speedup vs baseline: 1.9642x; 1.0095x over previous
//
#include <hip/hip_runtime.h>

// ---------------------------------------------------------------------------
// Fused QKV-projection + attention (B=8, C=2048, N=512), fp32 in/out.
// Precision: fp32 -> fp16 hi/lo split. Projections: full 3-term fp16 MFMA.
// Attention logits: 2.5-term (qh*kh + ql*kh; qh*kl dropped -> absmax 1.2e-3
// measured, threshold 4.6e-3).
// Round 8: VGPR BUDGET FIX via LDS occupancy forcing. Evidence across rounds:
// LDS<80KB (2 blocks/CU possible) -> compiler budget 128 VGPR -> Q spilled,
// per-tile reload = the whole runtime (R3/R5/R6/R7 all VGPR_Count=128);
// LDS>80KB (R2) -> budget 256. Our grid is 1 block/CU anyway, so declare
// kt[2][20480] (80KB, 64KB used) -> HW fits only 1 block/CU -> backend
// occupancy = 2 waves/EU -> budget 256 -> Q(128)+O(64) truly resident.
// Everything else identical to R7 (V kv-blocked, DPP row-max, single light
// barrier + own-half-normalized P, defer-max THR=8, volatile-asm Q loads).
// ---------------------------------------------------------------------------

typedef _Float16 half_t;
typedef __attribute__((ext_vector_type(8))) _Float16 half8;
typedef __attribute__((ext_vector_type(4))) _Float16 half4;
typedef __attribute__((ext_vector_type(4))) float    f32x4;

#define MFMA16x32(A_, B_, C_) __builtin_amdgcn_mfma_f32_16x16x32_f16((A_), (B_), (C_), 0, 0, 0)

// barrier that is ALSO a compiler memory fence, without draining vmcnt:
#define LIGHT_BARRIER() asm volatile("s_waitcnt lgkmcnt(0)\n\ts_barrier" ::: "memory")

__device__ __forceinline__ void gload_lds16(const void* g, void* l) {
  __builtin_amdgcn_global_load_lds(
      (const __attribute__((address_space(1))) void*)g,
      (__attribute__((address_space(3))) void*)l, 16, 0, 0);
}

// max-reduce over each 16-lane row via DPP (quad_perm xor1/xor2, row_ror 4/8).
__device__ __forceinline__ float dpp_max16(float x) {
  int t;
  t = __builtin_amdgcn_update_dpp(__float_as_int(x), __float_as_int(x), 0xB1, 0xF, 0xF, false);
  x = fmaxf(x, __int_as_float(t));
  t = __builtin_amdgcn_update_dpp(__float_as_int(x), __float_as_int(x), 0x4E, 0xF, 0xF, false);
  x = fmaxf(x, __int_as_float(t));
  t = __builtin_amdgcn_update_dpp(__float_as_int(x), __float_as_int(x), 0x124, 0xF, 0xF, false);
  x = fmaxf(x, __int_as_float(t));
  t = __builtin_amdgcn_update_dpp(__float_as_int(x), __float_as_int(x), 0x128, 0xF, 0xF, false);
  x = fmaxf(x, __int_as_float(t));
  return x;
}

// ---- split fp32 [rows][cols] -> fp16 [rows][2*cols] = [hi | lo] -------------
__global__ void split_hilo(const float* __restrict__ src, half_t* __restrict__ dst,
                           int rows, int cols) {
  int idx = blockIdx.x * 256 + threadIdx.x;
  int total = rows * cols / 4;
  if (idx >= total) return;
  f32x4 v = ((const f32x4*)src)[idx];
  int e = idx * 4;
  int r = e / cols, c = e % cols;
  half4 h, l;
#pragma unroll
  for (int j = 0; j < 4; ++j) {
    float f = v[j];
    _Float16 hh = (_Float16)f;
    h[j] = hh;
    l[j] = (_Float16)(f - (float)hh);
  }
  *(half4*)&dst[(size_t)r * (2 * cols) + c] = h;
  *(half4*)&dst[(size_t)r * (2 * cols) + c + cols] = l;
}

// ---- projection GEMM --------------------------------------------------------
// MODE 0: out[t][m]=hi, out[t][m+512]=lo   (q/k)
// MODE 1: out[(t>>5)*16384 + m*32 + (t&31)] = f16(val)  (v kv-blocked)
template <int MODE>
__global__ __launch_bounds__(256) void proj_gemm(
    const half_t* __restrict__ A, const half_t* __restrict__ Bm,
    const float* __restrict__ bias, half_t* __restrict__ out) {
  __shared__ half_t At[128 * 64];
  __shared__ half_t Bt[128 * 64];
  const int tid = threadIdx.x;
  const int lane = tid & 63, wv = tid >> 6;
  const int g = lane >> 4, li = lane & 15;
  const int wm = wv >> 1, wn = wv & 1;
  const int M0 = blockIdx.x * 128, N0 = blockIdx.y * 128;

  const f32x4 kZero = {0.f, 0.f, 0.f, 0.f};
  f32x4 acc[4][4];
#pragma unroll
  for (int i = 0; i < 4; ++i)
#pragma unroll
    for (int j = 0; j < 4; ++j) acc[i][j] = kZero;

  for (int kt = 0; kt < 24; ++kt) {
    const int kc = kt * 64;
    const int ab = kc & 1023;
    const int bb = (kc < 512) ? kc : (kc - 512);
    __syncthreads();
#pragma unroll
    for (int s2 = 0; s2 < 4; ++s2) {
      int bid = tid + 256 * s2;
      int row = bid >> 3, blk = bid & 7;
      half8 va = *(const half8*)&A[(size_t)(M0 + row) * 1024 + ab + blk * 8];
      *(half8*)&At[row * 64 + ((blk ^ (row & 7)) * 8)] = va;
      half8 vb = *(const half8*)&Bm[(size_t)(N0 + row) * 1024 + bb + blk * 8];
      *(half8*)&Bt[row * 64 + ((blk ^ (row & 7)) * 8)] = vb;
    }
    __syncthreads();
#pragma unroll
    for (int kk = 0; kk < 2; ++kk) {
      half8 af[4], bf[4];
#pragma unroll
      for (int i = 0; i < 4; ++i) {
        int ar = wm * 64 + i * 16 + li;
        af[i] = *(const half8*)&At[ar * 64 + (((4 * kk + g) ^ (ar & 7)) * 8)];
        int br = wn * 64 + i * 16 + li;
        bf[i] = *(const half8*)&Bt[br * 64 + (((4 * kk + g) ^ (br & 7)) * 8)];
      }
#pragma unroll
      for (int i = 0; i < 4; ++i)
#pragma unroll
        for (int j = 0; j < 4; ++j) acc[i][j] = MFMA16x32(af[i], bf[j], acc[i][j]);
    }
  }

  if (MODE == 0) {
#pragma unroll
    for (int i = 0; i < 4; ++i) {
      int trow = M0 + wm * 64 + i * 16 + 4 * g;
#pragma unroll
      for (int j = 0; j < 4; ++j) {
        int m = N0 + wn * 64 + j * 16 + li;
        float bs = bias[m];
#pragma unroll
        for (int r = 0; r < 4; ++r) {
          float v = acc[i][j][r] + bs;
          _Float16 hh = (_Float16)v;
          _Float16 ll = (_Float16)(v - (float)hh);
          out[(size_t)(trow + r) * 1024 + m] = hh;
          out[(size_t)(trow + r) * 1024 + m + 512] = ll;
        }
      }
    }
  } else {
#pragma unroll
    for (int i = 0; i < 4; ++i) {
      int m0r = M0 + wm * 64 + i * 16 + 4 * g;
#pragma unroll
      for (int r = 0; r < 4; ++r) {
        int m = m0r + r;
        float bs = bias[m];
#pragma unroll
        for (int j = 0; j < 4; ++j) {
          int tt = N0 + wn * 64 + j * 16 + li;
          out[(size_t)(tt >> 5) * 16384 + (size_t)m * 32 + (tt & 31)] =
              (_Float16)(acc[i][j][r] + bs);
        }
      }
    }
  }
}

// ---- flash attention v8 -----------------------------------------------------
// grid 256 (1 block/CU), 512 threads = 8 waves = 4 pair-groups x 16 q-rows.
// Wave pair: wbit splits kv (QK) and n (PV). K-hi tile double-buffered via
// global_load_lds. LDS deliberately >80KB (kt rows padded 16384->20480) so the
// HW fits only 1 block/CU -> compiler VGPR budget 256 -> Q/O register-resident.
__global__ __attribute__((amdgpu_flat_work_group_size(512, 512),
                          amdgpu_waves_per_eu(2, 2))) void flash_attn(
    const half_t* __restrict__ qs, const half_t* __restrict__ ks,
    const half_t* __restrict__ vblk, float* __restrict__ outp) {
  __shared__ half_t kt[2][20480];      // 2 x 40 KB declared (32 KB used each):
                                       // forces 1 block/CU -> 256-VGPR budget
  __shared__ half_t plds[4][16][40];   // P per pair-group [q16][kv32+pad16B]
  __shared__ float  tmx[4][2][16];     // per-tile half row-max [grp][wbit][row]
  __shared__ float  lx[4][16];         // final l exchange [grp][row]

  const int blk0 = blockIdx.x;
  const int logical = (blk0 & 7) * 32 + (blk0 >> 3);   // XCD-chunked (256%8==0)
  const int b  = logical >> 5;                         // batch = XCD
  const int c0 = (logical & 31) * 64;
  const int tid = threadIdx.x;
  const int wv = tid >> 6, lane = tid & 63;
  const int grp = wv >> 1, wbit = wv & 1;
  const int g = lane >> 4, li = lane & 15;
  const int qr0 = c0 + grp * 16;
  const int nh0 = wbit * 256;          // this wave's n-half for PV/output

  const char* kbytes = (const char*)(ks + (size_t)b * 2048 * 1024);

  // Q fragments pinned in registers via volatile asm (cannot be remat'd):
  // 16 rows, hi + lo (16 chunks each) = 128 VGPR.
  const half_t* qrow = qs + (size_t)(b * 2048 + qr0 + li) * 1024 + 8 * g;
  half8 qh[16], ql[16];
#pragma unroll
  for (int c = 0; c < 16; ++c) {
    const half_t* ah = qrow + c * 32;
    const half_t* al = qrow + 512 + c * 32;
    asm volatile("global_load_dwordx4 %0, %1, off" : "=v"(qh[c]) : "v"(ah));
    asm volatile("global_load_dwordx4 %0, %1, off" : "=v"(ql[c]) : "v"(al));
  }
  asm volatile("s_waitcnt vmcnt(0)" ::: "memory");

  const f32x4 kZero = {0.f, 0.f, 0.f, 0.f};
  f32x4 o[16];
#pragma unroll
  for (int i = 0; i < 16; ++i) o[i] = kZero;
  float mr[4] = {-3e38f, -3e38f, -3e38f, -3e38f};  // joint running max, rows 4g+r
  float m_li = -3e38f, l_li = 0.f;                 // joint running max/l, row li

  // stage K-hi tile: 32 rows x 1024 B = 2048 16B-segs, 4 per thread.
  auto STAGE = [&](int kv0s, int bufs) {
#pragma unroll
    for (int i2 = 0; i2 < 4; ++i2) {
      int seg = i2 * 512 + tid;
      int r = seg >> 6, bb = seg & 63;
      int bsrc = bb ^ (r & 7);
      gload_lds16(kbytes + (size_t)(kv0s + r) * 2048 + bsrc * 16,
                  (void*)&kt[bufs][seg * 8]);
    }
  };

  STAGE(0, 0);
  __syncthreads();
  int cur = 0;

#pragma unroll 1
  for (int t = 0; t < 64; ++t) {
    if (t + 1 < 64) STAGE((t + 1) * 32, cur ^ 1);   // prefetch next tile (async)

    // ---- QK: S[16q][16kv(this wave)] = (qh + ql) . kh^T, 4 MFMA chains ----
    const half_t* krow = &kt[cur][(wbit * 16 + li) * 512];
    const int swz = li & 7;
    f32x4 sA = kZero, sB = kZero, sC = kZero, sD = kZero;
#pragma unroll
    for (int c = 0; c < 16; c += 2) {
      half8 k0 = *(const half8*)&krow[((4 * c + g) ^ swz) * 8];
      half8 k1 = *(const half8*)&krow[((4 * c + 4 + g) ^ swz) * 8];
      sA = MFMA16x32(qh[c], k0, sA);
      sC = MFMA16x32(ql[c], k0, sC);
      sB = MFMA16x32(qh[c + 1], k1, sB);
      sD = MFMA16x32(ql[c + 1], k1, sD);
    }
    f32x4 sv = (sA + sC) + (sB + sD);

    // ---- per-row max of THIS half (DPP, pure VALU); P normalized by it ----
    float tm[4];
#pragma unroll
    for (int r = 0; r < 4; ++r) tm[r] = dpp_max16(sv[r]);
#pragma unroll
    for (int r = 0; r < 4; ++r) {
      float p = __expf(sv[r] - tm[r]);            // <= 1
      plds[grp][4 * g + r][li + 16 * wbit] = (half_t)p;
    }
    if (li == 0) {
#pragma unroll
      for (int r = 0; r < 4; ++r) tmx[grp][wbit][4 * g + r] = tm[r];
    }
    LIGHT_BARRIER();   // single exchange point: P + half-maxes visible

    // ---- joint max, defer-max (THR=8), pa rescale ----
    f32x4 t0 = *(const f32x4*)&tmx[grp][0][4 * g];
    f32x4 t1 = *(const f32x4*)&tmx[grp][1][4 * g];
    float tA = tmx[grp][0][li], tB = tmx[grp][1][li];
    float tf[4];
#pragma unroll
    for (int r = 0; r < 4; ++r) tf[r] = fmaxf(t0[r], t1[r]);
    int grow = (tf[0] > mr[0] + 8.f) | (tf[1] > mr[1] + 8.f) |
               (tf[2] > mr[2] + 8.f) | (tf[3] > mr[3] + 8.f);
    if (__any(grow)) {
      float al[4];
#pragma unroll
      for (int r = 0; r < 4; ++r) {
        float mn = fmaxf(mr[r], tf[r]);
        al[r] = __expf(mr[r] - mn);
        mr[r] = mn;
      }
      f32x4 av = {al[0], al[1], al[2], al[3]};
#pragma unroll
      for (int i = 0; i < 16; ++i) o[i] *= av;
      float mnli = fmaxf(m_li, fmaxf(tA, tB));
      l_li *= __expf(m_li - mnli);
      m_li = mnli;
    }
    // scale for this lane's pa fragment (cols 8g..8g+7 live in half g>>1):
    float sh = __expf(((g < 2) ? tA : tB) - m_li);   // <= e^8 (defer bound)
    half_t sh16 = (half_t)sh;
    half8 pa = *(const half8*)&plds[grp][li][8 * g];
#pragma unroll
    for (int e = 0; e < 8; ++e) pa[e] = pa[e] * sh16;

    // l harvested from the scaled pa fragment
    float lp = 0.f;
#pragma unroll
    for (int e = 0; e < 8; ++e) lp += (float)pa[e];
    lp += __shfl_xor(lp, 16);
    lp += __shfl_xor(lp, 32);
    l_li += lp;

    // ---- PV over this wave's n-half; V kv-blocked -> 1KB coalesced loads ----
    const half_t* vtile = vblk + ((size_t)(b * 64 + t)) * 16384 +
                          (size_t)nh0 * 32 + li * 32 + 8 * g;
#pragma unroll
    for (int ns = 0; ns < 16; ++ns) {
      half8 v0 = *(const half8*)(vtile + ns * 512);
      o[ns] = MFMA16x32(pa, v0, o[ns]);
    }

    __syncthreads();   // full fence: drain stage (vmcnt0), protect kt/plds/tmx
    cur ^= 1;
  }

  // ---- final normalization: l in li-layout, o rows are 4g+r ----
  if (wbit == 0 && g == 0) lx[grp][li] = l_li;
  __syncthreads();
  float inv[4];
#pragma unroll
  for (int r = 0; r < 4; ++r) inv[r] = 1.0f / (lx[grp][4 * g + r] * 22.62741699796952f);

  float* ob = outp + (size_t)b * 1048576 + qr0 + 4 * g;
#pragma unroll
  for (int ns = 0; ns < 16; ++ns) {
#pragma unroll
    for (int r = 0; r < 4; ++r) {
      ob[(size_t)(nh0 + ns * 16 + li) * 2048 + r] = o[ns][r] * inv[r];
    }
  }
}

// ---------------------------------------------------------------------------
extern "C" void kernel_launch(void* const* d_in, const int* in_sizes, int n_in,
                              void* d_out, int out_size, void* d_ws, size_t ws_size,
                              hipStream_t stream) {
  const float* x  = (const float*)d_in[0];
  const float* Wq = (const float*)d_in[1];
  const float* bq = (const float*)d_in[2];
  const float* Wk = (const float*)d_in[3];
  const float* bk = (const float*)d_in[4];
  const float* Wv = (const float*)d_in[5];
  const float* bv = (const float*)d_in[6];

  half_t* xs  = (half_t*)d_ws;                  // [16384][1024]
  half_t* qsb = xs  + (size_t)16384 * 1024;     // [16384][1024]
  half_t* ksb = qsb + (size_t)16384 * 1024;     // [16384][1024]
  half_t* vtb = ksb + (size_t)16384 * 1024;     // [512 blk][512 n][32 kv]
  half_t* wqs = vtb + (size_t)512 * 16384;      // [512][1024]
  half_t* wks = wqs + (size_t)512 * 1024;
  half_t* wvs = wks + (size_t)512 * 1024;

  split_hilo<<<dim3(16384 * 512 / 4 / 256), 256, 0, stream>>>(x, xs, 16384, 512);
  split_hilo<<<dim3(512 * 512 / 4 / 256), 256, 0, stream>>>(Wq, wqs, 512, 512);
  split_hilo<<<dim3(512 * 512 / 4 / 256), 256, 0, stream>>>(Wk, wks, 512, 512);
  split_hilo<<<dim3(512 * 512 / 4 / 256), 256, 0, stream>>>(Wv, wvs, 512, 512);

  proj_gemm<0><<<dim3(128, 4), 256, 0, stream>>>(xs, wqs, bq, qsb);
  proj_gemm<0><<<dim3(128, 4), 256, 0, stream>>>(xs, wks, bk, ksb);
  proj_gemm<1><<<dim3(4, 128), 256, 0, stream>>>(wvs, xs, bv, vtb);

  flash_attn<<<dim3(256), 512, 0, stream>>>(qsb, ksb, vtb, (float*)d_out);
}

// Round 9
// 303.741 us; speedup vs baseline: 3.3218x; 1.6912x over previous
//
#include <hip/hip_runtime.h>

// ---------------------------------------------------------------------------
// Fused QKV-projection + attention (B=8, C=2048, N=512), fp32 in/out.
// Precision: fp32 -> fp16 hi/lo split. Projections: full 3-term fp16 MFMA.
// Attention logits: 1.5-term (S = qh*kh; both cross-terms dropped).
// Error ledger (measured): full-3-term 9.77e-4, 2.5-term 1.22e-3 -> projected
// 1.5-term ~1.5e-3 vs threshold 4.57e-3 (P/V-fp16 floor dominates; softmax at
// sigma_s~22 is argmax-like, insensitive to small logit noise).
// Round 9: LATENCY FIX via register-pressure release. R8 showed 256-total
// budget (128 arch + 128 AGPR) fully consumed by Q(128)+O(64)+temps -> zero
// scheduler headroom -> ds_read/V-load latencies serialized (~15k cyc/tile vs
// ~2k work). Now: Q-hi only (64 regs), V prefetched into regs at tile top
// (before STAGE, so counted vmcnt hides L2 latency under QK+softmax),
// compact hi-only Q/K buffers (proj MODE 2). Structure else unchanged.
// ---------------------------------------------------------------------------

typedef _Float16 half_t;
typedef __attribute__((ext_vector_type(8))) _Float16 half8;
typedef __attribute__((ext_vector_type(4))) _Float16 half4;
typedef __attribute__((ext_vector_type(4))) float    f32x4;

#define MFMA16x32(A_, B_, C_) __builtin_amdgcn_mfma_f32_16x16x32_f16((A_), (B_), (C_), 0, 0, 0)

// barrier that is ALSO a compiler memory fence, without draining vmcnt:
#define LIGHT_BARRIER() asm volatile("s_waitcnt lgkmcnt(0)\n\ts_barrier" ::: "memory")

__device__ __forceinline__ void gload_lds16(const void* g, void* l) {
  __builtin_amdgcn_global_load_lds(
      (const __attribute__((address_space(1))) void*)g,
      (__attribute__((address_space(3))) void*)l, 16, 0, 0);
}

// max-reduce over each 16-lane row via DPP (quad_perm xor1/xor2, row_ror 4/8).
__device__ __forceinline__ float dpp_max16(float x) {
  int t;
  t = __builtin_amdgcn_update_dpp(__float_as_int(x), __float_as_int(x), 0xB1, 0xF, 0xF, false);
  x = fmaxf(x, __int_as_float(t));
  t = __builtin_amdgcn_update_dpp(__float_as_int(x), __float_as_int(x), 0x4E, 0xF, 0xF, false);
  x = fmaxf(x, __int_as_float(t));
  t = __builtin_amdgcn_update_dpp(__float_as_int(x), __float_as_int(x), 0x124, 0xF, 0xF, false);
  x = fmaxf(x, __int_as_float(t));
  t = __builtin_amdgcn_update_dpp(__float_as_int(x), __float_as_int(x), 0x128, 0xF, 0xF, false);
  x = fmaxf(x, __int_as_float(t));
  return x;
}

// ---- split fp32 [rows][cols] -> fp16 [rows][2*cols] = [hi | lo] -------------
__global__ void split_hilo(const float* __restrict__ src, half_t* __restrict__ dst,
                           int rows, int cols) {
  int idx = blockIdx.x * 256 + threadIdx.x;
  int total = rows * cols / 4;
  if (idx >= total) return;
  f32x4 v = ((const f32x4*)src)[idx];
  int e = idx * 4;
  int r = e / cols, c = e % cols;
  half4 h, l;
#pragma unroll
  for (int j = 0; j < 4; ++j) {
    float f = v[j];
    _Float16 hh = (_Float16)f;
    h[j] = hh;
    l[j] = (_Float16)(f - (float)hh);
  }
  *(half4*)&dst[(size_t)r * (2 * cols) + c] = h;
  *(half4*)&dst[(size_t)r * (2 * cols) + c + cols] = l;
}

// ---- projection GEMM --------------------------------------------------------
// MODE 2: out[t*512 + m] = f16(val)                       (q/k, hi-only compact)
// MODE 1: out[(t>>5)*16384 + m*32 + (t&31)] = f16(val)    (v kv-blocked)
template <int MODE>
__global__ __launch_bounds__(256) void proj_gemm(
    const half_t* __restrict__ A, const half_t* __restrict__ Bm,
    const float* __restrict__ bias, half_t* __restrict__ out) {
  __shared__ half_t At[128 * 64];
  __shared__ half_t Bt[128 * 64];
  const int tid = threadIdx.x;
  const int lane = tid & 63, wv = tid >> 6;
  const int g = lane >> 4, li = lane & 15;
  const int wm = wv >> 1, wn = wv & 1;
  const int M0 = blockIdx.x * 128, N0 = blockIdx.y * 128;

  const f32x4 kZero = {0.f, 0.f, 0.f, 0.f};
  f32x4 acc[4][4];
#pragma unroll
  for (int i = 0; i < 4; ++i)
#pragma unroll
    for (int j = 0; j < 4; ++j) acc[i][j] = kZero;

  for (int kt = 0; kt < 24; ++kt) {
    const int kc = kt * 64;
    const int ab = kc & 1023;
    const int bb = (kc < 512) ? kc : (kc - 512);
    __syncthreads();
#pragma unroll
    for (int s2 = 0; s2 < 4; ++s2) {
      int bid = tid + 256 * s2;
      int row = bid >> 3, blk = bid & 7;
      half8 va = *(const half8*)&A[(size_t)(M0 + row) * 1024 + ab + blk * 8];
      *(half8*)&At[row * 64 + ((blk ^ (row & 7)) * 8)] = va;
      half8 vb = *(const half8*)&Bm[(size_t)(N0 + row) * 1024 + bb + blk * 8];
      *(half8*)&Bt[row * 64 + ((blk ^ (row & 7)) * 8)] = vb;
    }
    __syncthreads();
#pragma unroll
    for (int kk = 0; kk < 2; ++kk) {
      half8 af[4], bf[4];
#pragma unroll
      for (int i = 0; i < 4; ++i) {
        int ar = wm * 64 + i * 16 + li;
        af[i] = *(const half8*)&At[ar * 64 + (((4 * kk + g) ^ (ar & 7)) * 8)];
        int br = wn * 64 + i * 16 + li;
        bf[i] = *(const half8*)&Bt[br * 64 + (((4 * kk + g) ^ (br & 7)) * 8)];
      }
#pragma unroll
      for (int i = 0; i < 4; ++i)
#pragma unroll
        for (int j = 0; j < 4; ++j) acc[i][j] = MFMA16x32(af[i], bf[j], acc[i][j]);
    }
  }

  if (MODE == 2) {
#pragma unroll
    for (int i = 0; i < 4; ++i) {
      int trow = M0 + wm * 64 + i * 16 + 4 * g;
#pragma unroll
      for (int j = 0; j < 4; ++j) {
        int m = N0 + wn * 64 + j * 16 + li;
        float bs = bias[m];
#pragma unroll
        for (int r = 0; r < 4; ++r) {
          out[(size_t)(trow + r) * 512 + m] = (_Float16)(acc[i][j][r] + bs);
        }
      }
    }
  } else {
#pragma unroll
    for (int i = 0; i < 4; ++i) {
      int m0r = M0 + wm * 64 + i * 16 + 4 * g;
#pragma unroll
      for (int r = 0; r < 4; ++r) {
        int m = m0r + r;
        float bs = bias[m];
#pragma unroll
        for (int j = 0; j < 4; ++j) {
          int tt = N0 + wn * 64 + j * 16 + li;
          out[(size_t)(tt >> 5) * 16384 + (size_t)m * 32 + (tt & 31)] =
              (_Float16)(acc[i][j][r] + bs);
        }
      }
    }
  }
}

// ---- flash attention v9 -----------------------------------------------------
// grid 256 (1 block/CU), 512 threads = 8 waves = 4 pair-groups x 16 q-rows.
// Wave pair: wbit splits kv (QK) and n (PV). K-hi tile double-buffered via
// global_load_lds. Q-hi register-resident (64 VGPR); V prefetched into regs
// at tile top (before STAGE -> counted vmcnt, L2 latency hidden under QK).
// LDS kept >80KB so HW fits exactly 1 block/CU (grid balance + 256-reg budget).
__global__ __attribute__((amdgpu_flat_work_group_size(512, 512),
                          amdgpu_waves_per_eu(2, 2))) void flash_attn(
    const half_t* __restrict__ qs, const half_t* __restrict__ ks,
    const half_t* __restrict__ vblk, float* __restrict__ outp) {
  __shared__ half_t kt[2][20480];      // 2 x 40 KB declared (32 KB used each)
  __shared__ half_t plds[4][16][40];   // P per pair-group [q16][kv32+pad16B]
  __shared__ float  tmx[4][2][16];     // per-tile half row-max [grp][wbit][row]
  __shared__ float  lx[4][16];         // final l exchange [grp][row]

  const int blk0 = blockIdx.x;
  const int logical = (blk0 & 7) * 32 + (blk0 >> 3);   // XCD-chunked (256%8==0)
  const int b  = logical >> 5;                         // batch = XCD
  const int c0 = (logical & 31) * 64;
  const int tid = threadIdx.x;
  const int wv = tid >> 6, lane = tid & 63;
  const int grp = wv >> 1, wbit = wv & 1;
  const int g = lane >> 4, li = lane & 15;
  const int qr0 = c0 + grp * 16;
  const int nh0 = wbit * 256;          // this wave's n-half for PV/output

  const char* kbytes = (const char*)(ks + (size_t)b * 2048 * 512);

  // Q-hi fragments pinned in registers (volatile asm: loaded exactly once):
  // 16 rows x 512 cols = 16 half8 = 64 VGPR.
  const half_t* qrow = qs + (size_t)(b * 2048 + qr0 + li) * 512 + 8 * g;
  half8 qh[16];
#pragma unroll
  for (int c = 0; c < 16; ++c) {
    const half_t* ah = qrow + c * 32;
    asm volatile("global_load_dwordx4 %0, %1, off" : "=v"(qh[c]) : "v"(ah));
  }
  asm volatile("s_waitcnt vmcnt(0)" ::: "memory");

  const f32x4 kZero = {0.f, 0.f, 0.f, 0.f};
  f32x4 o[16];
#pragma unroll
  for (int i = 0; i < 16; ++i) o[i] = kZero;
  float mr[4] = {-3e38f, -3e38f, -3e38f, -3e38f};  // joint running max, rows 4g+r
  float m_li = -3e38f, l_li = 0.f;                 // joint running max/l, row li

  // stage K-hi tile: 32 rows x 1024 B (contiguous) = 2048 16B-segs, 4/thread.
  auto STAGE = [&](int kv0s, int bufs) {
#pragma unroll
    for (int i2 = 0; i2 < 4; ++i2) {
      int seg = i2 * 512 + tid;
      int r = seg >> 6, bb = seg & 63;
      int bsrc = bb ^ (r & 7);
      gload_lds16(kbytes + (size_t)(kv0s + r) * 1024 + bsrc * 16,
                  (void*)&kt[bufs][seg * 8]);
    }
  };

  STAGE(0, 0);
  __syncthreads();
  int cur = 0;

#pragma unroll 1
  for (int t = 0; t < 64; ++t) {
    // ---- V prefetch for THIS tile (issued first -> counted vmcnt) ----
    const half_t* vtile = vblk + ((size_t)(b * 64 + t)) * 16384 +
                          (size_t)nh0 * 32 + li * 32 + 8 * g;
    half8 vreg[16];
#pragma unroll
    for (int ns = 0; ns < 16; ++ns) vreg[ns] = *(const half8*)(vtile + ns * 512);

    if (t + 1 < 64) STAGE((t + 1) * 32, cur ^ 1);   // prefetch next K tile

    // ---- QK: S[16q][16kv(this wave)] = qh . kh^T, 2 MFMA chains ----
    const half_t* krow = &kt[cur][(wbit * 16 + li) * 512];
    const int swz = li & 7;
    f32x4 sA = kZero, sB = kZero;
#pragma unroll
    for (int c = 0; c < 16; c += 2) {
      half8 k0 = *(const half8*)&krow[((4 * c + g) ^ swz) * 8];
      half8 k1 = *(const half8*)&krow[((4 * c + 4 + g) ^ swz) * 8];
      sA = MFMA16x32(qh[c], k0, sA);
      sB = MFMA16x32(qh[c + 1], k1, sB);
    }
    f32x4 sv = sA + sB;

    // ---- per-row max of THIS half (DPP, pure VALU); P normalized by it ----
    float tm[4];
#pragma unroll
    for (int r = 0; r < 4; ++r) tm[r] = dpp_max16(sv[r]);
#pragma unroll
    for (int r = 0; r < 4; ++r) {
      float p = __expf(sv[r] - tm[r]);            // <= 1
      plds[grp][4 * g + r][li + 16 * wbit] = (half_t)p;
    }
    if (li == 0) {
#pragma unroll
      for (int r = 0; r < 4; ++r) tmx[grp][wbit][4 * g + r] = tm[r];
    }
    LIGHT_BARRIER();   // single exchange point: P + half-maxes visible

    // ---- joint max, defer-max (THR=8), pa rescale ----
    f32x4 t0 = *(const f32x4*)&tmx[grp][0][4 * g];
    f32x4 t1 = *(const f32x4*)&tmx[grp][1][4 * g];
    float tA = tmx[grp][0][li], tB = tmx[grp][1][li];
    float tf[4];
#pragma unroll
    for (int r = 0; r < 4; ++r) tf[r] = fmaxf(t0[r], t1[r]);
    int grow = (tf[0] > mr[0] + 8.f) | (tf[1] > mr[1] + 8.f) |
               (tf[2] > mr[2] + 8.f) | (tf[3] > mr[3] + 8.f);
    if (__any(grow)) {
      float al[4];
#pragma unroll
      for (int r = 0; r < 4; ++r) {
        float mn = fmaxf(mr[r], tf[r]);
        al[r] = __expf(mr[r] - mn);
        mr[r] = mn;
      }
      f32x4 av = {al[0], al[1], al[2], al[3]};
#pragma unroll
      for (int i = 0; i < 16; ++i) o[i] *= av;
      float mnli = fmaxf(m_li, fmaxf(tA, tB));
      l_li *= __expf(m_li - mnli);
      m_li = mnli;
    }
    // scale for this lane's pa fragment (cols 8g..8g+7 live in half g>>1):
    float sh = __expf(((g < 2) ? tA : tB) - m_li);   // <= e^8 (defer bound)
    half_t sh16 = (half_t)sh;
    half8 pa = *(const half8*)&plds[grp][li][8 * g];
#pragma unroll
    for (int e = 0; e < 8; ++e) pa[e] = pa[e] * sh16;

    // l harvested from the scaled pa fragment
    float lp = 0.f;
#pragma unroll
    for (int e = 0; e < 8; ++e) lp += (float)pa[e];
    lp += __shfl_xor(lp, 16);
    lp += __shfl_xor(lp, 32);
    l_li += lp;

    // ---- PV from prefetched V registers ----
#pragma unroll
    for (int ns = 0; ns < 16; ++ns) {
      o[ns] = MFMA16x32(pa, vreg[ns], o[ns]);
    }

    __syncthreads();   // full fence: drain stage (vmcnt0), protect kt/plds/tmx
    cur ^= 1;
  }

  // ---- final normalization: l in li-layout, o rows are 4g+r ----
  if (wbit == 0 && g == 0) lx[grp][li] = l_li;
  __syncthreads();
  float inv[4];
#pragma unroll
  for (int r = 0; r < 4; ++r) inv[r] = 1.0f / (lx[grp][4 * g + r] * 22.62741699796952f);

  float* ob = outp + (size_t)b * 1048576 + qr0 + 4 * g;
#pragma unroll
  for (int ns = 0; ns < 16; ++ns) {
#pragma unroll
    for (int r = 0; r < 4; ++r) {
      ob[(size_t)(nh0 + ns * 16 + li) * 2048 + r] = o[ns][r] * inv[r];
    }
  }
}

// ---------------------------------------------------------------------------
extern "C" void kernel_launch(void* const* d_in, const int* in_sizes, int n_in,
                              void* d_out, int out_size, void* d_ws, size_t ws_size,
                              hipStream_t stream) {
  const float* x  = (const float*)d_in[0];
  const float* Wq = (const float*)d_in[1];
  const float* bq = (const float*)d_in[2];
  const float* Wk = (const float*)d_in[3];
  const float* bk = (const float*)d_in[4];
  const float* Wv = (const float*)d_in[5];
  const float* bv = (const float*)d_in[6];

  half_t* xs  = (half_t*)d_ws;                  // [16384][1024] hi|lo
  half_t* qsb = xs  + (size_t)16384 * 1024;     // [16384][512]  hi only
  half_t* ksb = qsb + (size_t)16384 * 512;      // [16384][512]  hi only
  half_t* vtb = ksb + (size_t)16384 * 512;      // [512 blk][512 n][32 kv]
  half_t* wqs = vtb + (size_t)512 * 16384;      // [512][1024]
  half_t* wks = wqs + (size_t)512 * 1024;
  half_t* wvs = wks + (size_t)512 * 1024;

  split_hilo<<<dim3(16384 * 512 / 4 / 256), 256, 0, stream>>>(x, xs, 16384, 512);
  split_hilo<<<dim3(512 * 512 / 4 / 256), 256, 0, stream>>>(Wq, wqs, 512, 512);
  split_hilo<<<dim3(512 * 512 / 4 / 256), 256, 0, stream>>>(Wk, wks, 512, 512);
  split_hilo<<<dim3(512 * 512 / 4 / 256), 256, 0, stream>>>(Wv, wvs, 512, 512);

  proj_gemm<2><<<dim3(128, 4), 256, 0, stream>>>(xs, wqs, bq, qsb);
  proj_gemm<2><<<dim3(128, 4), 256, 0, stream>>>(xs, wks, bk, ksb);
  proj_gemm<1><<<dim3(4, 128), 256, 0, stream>>>(wvs, xs, bv, vtb);

  flash_attn<<<dim3(256), 512, 0, stream>>>(qsb, ksb, vtb, (float*)d_out);
}